// Round 4
// baseline (1168.634 us; speedup 1.0000x reference)
//
#include <hip/hip_runtime.h>
#include <math.h>

#define BB 2
#define SS 2048
#define DD 512
#define HH 8
#define HDD 64
#define RANKK 128
#define DFFF 1024

typedef short bf16x8 __attribute__((ext_vector_type(8)));
typedef float f32x4 __attribute__((ext_vector_type(4)));

__device__ __forceinline__ short f2b(float f) {
  union { float f; unsigned u; } v; v.f = f;
  unsigned r = v.u + 0x7FFF + ((v.u >> 16) & 1);
  return (short)(r >> 16);
}
__device__ __forceinline__ float b2f(short s) {
  union { unsigned u; float f; } v; v.u = ((unsigned)(unsigned short)s) << 16;
  return v.f;
}

__device__ __forceinline__ float wsum(float v) {
#pragma unroll
  for (int off = 32; off > 0; off >>= 1) v += __shfl_xor(v, off, 64);
  return v;
}

// ---------------- rmsnorm fp32 ----------------
__global__ void tsa_rmsnorm(const float* __restrict__ x, const float* __restrict__ w,
                            float* __restrict__ o, int rows) {
  int wid = blockIdx.x * 4 + (threadIdx.x >> 6);
  int lane = threadIdx.x & 63;
  if (wid >= rows) return;
  const float* xp = x + (size_t)wid * DD + lane * 8;
  float4 a = *(const float4*)xp;
  float4 b = *(const float4*)(xp + 4);
  float ss = a.x*a.x + a.y*a.y + a.z*a.z + a.w*a.w
           + b.x*b.x + b.y*b.y + b.z*b.z + b.w*b.w;
  ss = wsum(ss);
  float r = rsqrtf(ss * (1.0f / DD) + 1e-6f);
  const float* wp = w + lane * 8;
  float4 wa = *(const float4*)wp, wb = *(const float4*)(wp + 4);
  float* op = o + (size_t)wid * DD + lane * 8;
  float4 oa = {a.x*r*wa.x, a.y*r*wa.y, a.z*r*wa.z, a.w*r*wa.w};
  float4 ob = {b.x*r*wb.x, b.y*r*wb.y, b.z*r*wb.z, b.w*r*wb.w};
  *(float4*)op = oa;
  *(float4*)(op + 4) = ob;
}

// ---------------- RoPE fp32 in-place ----------------
__global__ void tsa_rope(float* __restrict__ q, float* __restrict__ k) {
  int idx = blockIdx.x * 256 + threadIdx.x;
  int i = idx & 31;
  int h = (idx >> 5) & 7;
  int s = (idx >> 8) & (SS - 1);
  int b = idx >> 19;
  float inv = exp2f(-(float)i * (13.287712379549449f / 32.0f));
  float ang = (float)s * inv;
  float sn, cs;
  sincosf(ang, &sn, &cs);
  size_t base = ((size_t)(b * SS + s)) * DD + h * HDD + i;
  float q1 = q[base], q2 = q[base + 32];
  q[base]      = q1 * cs - q2 * sn;
  q[base + 32] = q2 * cs + q1 * sn;
  float k1 = k[base], k2 = k[base + 32];
  k[base]      = k1 * cs - k2 * sn;
  k[base + 32] = k2 * cs + k1 * sn;
}

// ---------------- fp32 -> bf16 convert ----------------
__global__ void cvtb(const float* __restrict__ in, short* __restrict__ out, int n) {
  int i = (blockIdx.x * 256 + threadIdx.x) * 4;
  if (i >= n) return;
  float4 v = *(const float4*)(in + i);
  short4 o; o.x = f2b(v.x); o.y = f2b(v.y); o.z = f2b(v.z); o.w = f2b(v.w);
  *(short4*)(out + i) = o;
}

// ======================= split-precision GEMM =======================
template <int BL, bool SPLIT, bool TRILA, int OM>
__global__ __launch_bounds__(256) void sgemm(const float* __restrict__ A,
                                             const float* __restrict__ Bm,
                                             const float* __restrict__ ADD,
                                             float* __restrict__ C,
                                             int M, int N, int K,
                                             long long sA, long long sB, long long sC) {
  A += (long long)blockIdx.z * sA;
  Bm += (long long)blockIdx.z * sB;
  C += (long long)blockIdx.z * sC;
  __shared__ short Ah[128 * 32];
  __shared__ short Al[SPLIT ? 128 * 32 : 64];
  __shared__ short Bh[128 * 32];
  __shared__ short Bl[SPLIT ? 128 * 32 : 64];
  const int tid = threadIdx.x, l = tid & 63, w = tid >> 6;
  const int wr = (w >> 1) * 64, wc = (w & 1) * 64;
  const int bm = blockIdx.y * 128, bn = blockIdx.x * 128;
  f32x4 acc[4][4] = {};
  const int kend = TRILA ? min(K, bm + 128) : K;
  for (int k0 = 0; k0 < kend; k0 += 32) {
#pragma unroll
    for (int i = 0; i < 4; i++) {
      int lin = i * 256 + tid;
      int row = lin >> 3, f4 = lin & 7;
      int gr = min(bm + row, M - 1);
      float4 v = *(const float4*)(A + (size_t)gr * K + k0 + f4 * 4);
      if (TRILA) {
        int kc = k0 + f4 * 4;
        if (kc + 0 > gr) v.x = 0.0f;
        if (kc + 1 > gr) v.y = 0.0f;
        if (kc + 2 > gr) v.z = 0.0f;
        if (kc + 3 > gr) v.w = 0.0f;
      }
      int off = row * 32 + (((f4 >> 1) ^ ((row >> 1) & 3)) << 3) + (f4 & 1) * 4;
      short4 hh;
      hh.x = f2b(v.x); hh.y = f2b(v.y); hh.z = f2b(v.z); hh.w = f2b(v.w);
      *(short4*)(Ah + off) = hh;
      if (SPLIT) {
        short4 lo;
        lo.x = f2b(v.x - b2f(hh.x)); lo.y = f2b(v.y - b2f(hh.y));
        lo.z = f2b(v.z - b2f(hh.z)); lo.w = f2b(v.w - b2f(hh.w));
        *(short4*)(Al + off) = lo;
      }
    }
    if (BL == 0) {
#pragma unroll
      for (int i = 0; i < 4; i++) {
        int lin = i * 256 + tid;
        int row = lin >> 3, f4 = lin & 7;
        int gr = min(bn + row, N - 1);
        float4 v = *(const float4*)(Bm + (size_t)gr * K + k0 + f4 * 4);
        int off = row * 32 + (((f4 >> 1) ^ ((row >> 1) & 3)) << 3) + (f4 & 1) * 4;
        short4 hh;
        hh.x = f2b(v.x); hh.y = f2b(v.y); hh.z = f2b(v.z); hh.w = f2b(v.w);
        *(short4*)(Bh + off) = hh;
        if (SPLIT) {
          short4 lo;
          lo.x = f2b(v.x - b2f(hh.x)); lo.y = f2b(v.y - b2f(hh.y));
          lo.z = f2b(v.z - b2f(hh.z)); lo.w = f2b(v.w - b2f(hh.w));
          *(short4*)(Bl + off) = lo;
        }
      }
    } else {
#pragma unroll
      for (int i = 0; i < 4; i++) {
        int lin = i * 256 + tid;
        int kk = lin >> 5, f4n = lin & 31;
        float4 v = *(const float4*)(Bm + (size_t)(k0 + kk) * N + bn + f4n * 4);
        float vv[4] = {v.x, v.y, v.z, v.w};
#pragma unroll
        for (int e = 0; e < 4; e++) {
          int row = f4n * 4 + e;
          int off = row * 32 + (((kk >> 3) ^ ((row >> 1) & 3)) << 3) + (kk & 7);
          short hi = f2b(vv[e]);
          Bh[off] = hi;
          if (SPLIT) Bl[off] = f2b(vv[e] - b2f(hi));
        }
      }
    }
    __syncthreads();
    bf16x8 ah[4], bh[4], al_[4], bl_[4];
#pragma unroll
    for (int m = 0; m < 4; m++) {
      int r = wr + m * 16 + (l & 15);
      int go = (((l >> 4) ^ ((r >> 1) & 3)) << 3);
      ah[m] = *(const bf16x8*)(Ah + r * 32 + go);
      if (SPLIT) al_[m] = *(const bf16x8*)(Al + r * 32 + go);
    }
#pragma unroll
    for (int n = 0; n < 4; n++) {
      int r = wc + n * 16 + (l & 15);
      int go = (((l >> 4) ^ ((r >> 1) & 3)) << 3);
      bh[n] = *(const bf16x8*)(Bh + r * 32 + go);
      if (SPLIT) bl_[n] = *(const bf16x8*)(Bl + r * 32 + go);
    }
#pragma unroll
    for (int m = 0; m < 4; m++)
#pragma unroll
      for (int n = 0; n < 4; n++) {
        acc[m][n] = __builtin_amdgcn_mfma_f32_16x16x32_bf16(ah[m], bh[n], acc[m][n], 0, 0, 0);
        if (SPLIT) {
          acc[m][n] = __builtin_amdgcn_mfma_f32_16x16x32_bf16(ah[m], bl_[n], acc[m][n], 0, 0, 0);
          acc[m][n] = __builtin_amdgcn_mfma_f32_16x16x32_bf16(al_[m], bh[n], acc[m][n], 0, 0, 0);
        }
      }
    __syncthreads();
  }
#pragma unroll
  for (int m = 0; m < 4; m++)
#pragma unroll
    for (int n = 0; n < 4; n++) {
      int gn = bn + wc + n * 16 + (l & 15);
#pragma unroll
      for (int j = 0; j < 4; j++) {
        int gm = bm + wr + m * 16 + (l >> 4) * 4 + j;
        if (gm >= M || gn >= N) continue;
        float v = acc[m][n][j];
        if (OM == 0) {
          C[(size_t)gm * N + gn] = v;
        } else if (OM == 1) {
          int b = gm >> 11, s2 = gm & (SS - 1);
          int hh2 = gn >> 6, d = gn & 63;
          C[(((size_t)(b * HH + hh2)) * HDD + d) * SS + s2] = v;
        } else if (OM == 2) {
          int b = gm >> 11, s2 = gm & (SS - 1);
          C[((size_t)b * DD + gn) * SS + s2] = v;
        } else {
          size_t off = (size_t)gm * N + gn;
          C[off] = v + ADD[off];
        }
      }
    }
}

// ======================= split-precision flash attention =======================
__global__ __launch_bounds__(256) void attn_f(const float* __restrict__ q,
                                              const float* __restrict__ k,
                                              const float* __restrict__ vT,
                                              float* __restrict__ attn) {
  const int h = blockIdx.y, b = blockIdx.z;
  const int q0 = blockIdx.x * 64;
  const int tid = threadIdx.x, w = tid >> 6, l = tid & 63;
  const int lg = l >> 4, ll = l & 15;
  __shared__ short Kh[64 * 64], Kl[64 * 64];
  __shared__ short Vh[64 * 64], Vl[64 * 64];
  __shared__ short Ph[64 * 64], Pl[64 * 64];

#pragma unroll
  for (int i = 0; i < 4; i++) {
    int lin = i * 256 + tid;
    int row = lin >> 4, f4 = lin & 15;
    float4 v = *(const float4*)(q + ((size_t)(b * SS + q0 + row)) * DD + h * HDD + f4 * 4);
    int off = row * 64 + (((f4 >> 1) ^ (row & 7)) << 3) + (f4 & 1) * 4;
    short4 hh, lo;
    hh.x = f2b(v.x); hh.y = f2b(v.y); hh.z = f2b(v.z); hh.w = f2b(v.w);
    lo.x = f2b(v.x - b2f(hh.x)); lo.y = f2b(v.y - b2f(hh.y));
    lo.z = f2b(v.z - b2f(hh.z)); lo.w = f2b(v.w - b2f(hh.w));
    *(short4*)(Ph + off) = hh;
    *(short4*)(Pl + off) = lo;
  }
  __syncthreads();
  bf16x8 qfh[2], qfl[2];
  {
    int qr = w * 16 + ll;
#pragma unroll
    for (int ks = 0; ks < 2; ks++) {
      int g = (ks * 4 + lg) ^ (qr & 7);
      qfh[ks] = *(const bf16x8*)(Ph + qr * 64 + g * 8);
      qfl[ks] = *(const bf16x8*)(Pl + qr * 64 + g * 8);
    }
  }
  __syncthreads();

  f32x4 o[4] = {};
  float mrow[4] = {-1e30f, -1e30f, -1e30f, -1e30f};
  float lsum[4] = {};
  const int qrow0 = q0 + w * 16 + lg * 4;
  const int ntiles = blockIdx.x + 1;

  for (int kt = 0; kt < ntiles; kt++) {
#pragma unroll
    for (int i = 0; i < 4; i++) {
      int lin = i * 256 + tid;
      int row = lin >> 4, f4 = lin & 15;
      int off = row * 64 + (((f4 >> 1) ^ (row & 7)) << 3) + (f4 & 1) * 4;
      float4 kv = *(const float4*)(k + ((size_t)(b * SS + kt * 64 + row)) * DD + h * HDD + f4 * 4);
      short4 hh, lo;
      hh.x = f2b(kv.x); hh.y = f2b(kv.y); hh.z = f2b(kv.z); hh.w = f2b(kv.w);
      lo.x = f2b(kv.x - b2f(hh.x)); lo.y = f2b(kv.y - b2f(hh.y));
      lo.z = f2b(kv.z - b2f(hh.z)); lo.w = f2b(kv.w - b2f(hh.w));
      *(short4*)(Kh + off) = hh;
      *(short4*)(Kl + off) = lo;
      float4 vv = *(const float4*)(vT + (((size_t)(b * HH + h)) * HDD + row) * SS + kt * 64 + f4 * 4);
      hh.x = f2b(vv.x); hh.y = f2b(vv.y); hh.z = f2b(vv.z); hh.w = f2b(vv.w);
      lo.x = f2b(vv.x - b2f(hh.x)); lo.y = f2b(vv.y - b2f(hh.y));
      lo.z = f2b(vv.z - b2f(hh.z)); lo.w = f2b(vv.w - b2f(hh.w));
      *(short4*)(Vh + off) = hh;
      *(short4*)(Vl + off) = lo;
    }
    __syncthreads();

    f32x4 sv[4] = {};
#pragma unroll
    for (int nf = 0; nf < 4; nf++) {
      int r = nf * 16 + ll;
#pragma unroll
      for (int ks = 0; ks < 2; ks++) {
        int g = (ks * 4 + lg) ^ (r & 7);
        bf16x8 kh = *(const bf16x8*)(Kh + r * 64 + g * 8);
        bf16x8 kl = *(const bf16x8*)(Kl + r * 64 + g * 8);
        sv[nf] = __builtin_amdgcn_mfma_f32_16x16x32_bf16(qfh[ks], kh, sv[nf], 0, 0, 0);
        sv[nf] = __builtin_amdgcn_mfma_f32_16x16x32_bf16(qfh[ks], kl, sv[nf], 0, 0, 0);
        sv[nf] = __builtin_amdgcn_mfma_f32_16x16x32_bf16(qfl[ks], kh, sv[nf], 0, 0, 0);
      }
    }
#pragma unroll
    for (int nf = 0; nf < 4; nf++) {
      int kpos = kt * 64 + nf * 16 + ll;
#pragma unroll
      for (int j = 0; j < 4; j++) {
        float v = sv[nf][j] * 0.125f;
        sv[nf][j] = (kpos > qrow0 + j) ? -1e30f : v;
      }
    }
    float cf[4];
#pragma unroll
    for (int j = 0; j < 4; j++) {
      float r = fmaxf(fmaxf(sv[0][j], sv[1][j]), fmaxf(sv[2][j], sv[3][j]));
      r = fmaxf(r, __shfl_xor(r, 1)); r = fmaxf(r, __shfl_xor(r, 2));
      r = fmaxf(r, __shfl_xor(r, 4)); r = fmaxf(r, __shfl_xor(r, 8));
      float mn = fmaxf(mrow[j], r);
      cf[j] = __expf(mrow[j] - mn);
      mrow[j] = mn;
    }
    float ps[4] = {};
#pragma unroll
    for (int nf = 0; nf < 4; nf++)
#pragma unroll
      for (int j = 0; j < 4; j++) {
        float p = __expf(sv[nf][j] - mrow[j]);
        sv[nf][j] = p;
        ps[j] += p;
      }
#pragma unroll
    for (int j = 0; j < 4; j++) {
      float r = ps[j];
      r += __shfl_xor(r, 1); r += __shfl_xor(r, 2);
      r += __shfl_xor(r, 4); r += __shfl_xor(r, 8);
      lsum[j] = lsum[j] * cf[j] + r;
    }
#pragma unroll
    for (int nf = 0; nf < 4; nf++)
#pragma unroll
      for (int j = 0; j < 4; j++) o[nf][j] *= cf[j];
#pragma unroll
    for (int nf = 0; nf < 4; nf++)
#pragma unroll
      for (int j = 0; j < 4; j++) {
        int rowP = w * 16 + lg * 4 + j;
        int col = nf * 16 + ll;
        int off = rowP * 64 + (((col >> 3) ^ (rowP & 7)) << 3) + (col & 7);
        float p = sv[nf][j];
        short hi = f2b(p);
        Ph[off] = hi;
        Pl[off] = f2b(p - b2f(hi));
      }
    __syncthreads();
    bf16x8 pfh[2], pfl[2];
    {
      int rowA = w * 16 + ll;
#pragma unroll
      for (int ks = 0; ks < 2; ks++) {
        int g = (ks * 4 + lg) ^ (rowA & 7);
        pfh[ks] = *(const bf16x8*)(Ph + rowA * 64 + g * 8);
        pfl[ks] = *(const bf16x8*)(Pl + rowA * 64 + g * 8);
      }
    }
#pragma unroll
    for (int nf = 0; nf < 4; nf++) {
      int r = nf * 16 + ll;
#pragma unroll
      for (int ks = 0; ks < 2; ks++) {
        int g = (ks * 4 + lg) ^ (r & 7);
        bf16x8 vh = *(const bf16x8*)(Vh + r * 64 + g * 8);
        bf16x8 vl = *(const bf16x8*)(Vl + r * 64 + g * 8);
        o[nf] = __builtin_amdgcn_mfma_f32_16x16x32_bf16(pfh[ks], vh, o[nf], 0, 0, 0);
        o[nf] = __builtin_amdgcn_mfma_f32_16x16x32_bf16(pfh[ks], vl, o[nf], 0, 0, 0);
        o[nf] = __builtin_amdgcn_mfma_f32_16x16x32_bf16(pfl[ks], vh, o[nf], 0, 0, 0);
      }
    }
    __syncthreads();
  }
  float inv[4];
#pragma unroll
  for (int j = 0; j < 4; j++) inv[j] = 1.0f / lsum[j];
#pragma unroll
  for (int nf = 0; nf < 4; nf++)
#pragma unroll
    for (int j = 0; j < 4; j++)
      attn[((size_t)(b * SS + qrow0 + j)) * DD + h * HDD + nf * 16 + ll] = o[nf][j] * inv[j];
}

// ======================= ALIF scan: deep prefetch + fast sigmoid =======================
#define ACH 32
__global__ __launch_bounds__(64) void tsa_alif2(const float* __restrict__ mixed,
                                                const float* __restrict__ x,
                                                const float* __restrict__ bt,
                                                const float* __restrict__ asw,
                                                float* __restrict__ h2) {
  int tid = blockIdx.x * 64 + threadIdx.x;  // 16 blocks x 64
  int b = tid >> 9, d = tid & 511;
  const float btd = bt[d], asd = asw[d];
  const float* mp = mixed + (size_t)b * SS * DD + d;
  const float* xp = x + (size_t)b * SS * DD + d;
  float* hp = h2 + (size_t)b * SS * DD + d;
  float vmem = 0.0f, ad = 0.0f;
  float mA[ACH], xA[ACH], mB[ACH], xB[ACH];
#pragma unroll
  for (int j = 0; j < ACH; j++) {
    mA[j] = mp[(size_t)j * DD];
    xA[j] = xp[(size_t)j * DD];
  }
  for (int t0 = 0; t0 < SS; t0 += 2 * ACH) {
    // prefetch B chunk (t0+ACH) — always exists
#pragma unroll
    for (int j = 0; j < ACH; j++) {
      mB[j] = mp[(size_t)(t0 + ACH + j) * DD];
      xB[j] = xp[(size_t)(t0 + ACH + j) * DD];
    }
    // compute A chunk (t0)
#pragma unroll
    for (int j = 0; j < ACH; j++) {
      float m = mA[j];
      vmem = fmaf(0.99f, vmem, m);
      float th = fmaf(asd, ad, btd);
      float e = __expf(-25.0f * (vmem - th));
      float s = __builtin_amdgcn_rcpf(1.0f + e);
      vmem -= s * th;
      ad = fmaf(0.95f, ad, s);
      hp[(size_t)(t0 + j) * DD] = xA[j] + m + s;
    }
    // prefetch A chunk (t0+2*ACH)
    if (t0 + 2 * ACH < SS) {
#pragma unroll
      for (int j = 0; j < ACH; j++) {
        mA[j] = mp[(size_t)(t0 + 2 * ACH + j) * DD];
        xA[j] = xp[(size_t)(t0 + 2 * ACH + j) * DD];
      }
    }
    // compute B chunk (t0+ACH)
#pragma unroll
    for (int j = 0; j < ACH; j++) {
      float m = mB[j];
      vmem = fmaf(0.99f, vmem, m);
      float th = fmaf(asd, ad, btd);
      float e = __expf(-25.0f * (vmem - th));
      float s = __builtin_amdgcn_rcpf(1.0f + e);
      vmem -= s * th;
      ad = fmaf(0.95f, ad, s);
      hp[(size_t)(t0 + ACH + j) * DD] = xB[j] + m + s;
    }
  }
}

// ======================= tree kernels (fp32, levels 0..4) =======================
__global__ void tree_reduce_f(const float* __restrict__ sin_, const float* __restrict__ tn1,
                              float* __restrict__ nb, int Sn) {
  int wid = blockIdx.x * 4 + (threadIdx.x >> 6);
  int lane = threadIdx.x & 63;
  int rows = BB * Sn;
  if (wid >= rows) return;
  int b = wid / Sn, j = wid - b * Sn;
  const float* r0 = sin_ + ((size_t)(b * 2 * Sn + 2 * j)) * DD + lane * 8;
  const float* r1 = r0 + DD;
  float4 a0 = *(const float4*)r0, a1 = *(const float4*)(r0 + 4);
  float4 b0 = *(const float4*)r1, b1 = *(const float4*)(r1 + 4);
  float ra[8] = {a0.x + b0.x, a0.y + b0.y, a0.z + b0.z, a0.w + b0.w,
                 a1.x + b1.x, a1.y + b1.y, a1.z + b1.z, a1.w + b1.w};
  float ss = 0.0f;
#pragma unroll
  for (int i = 0; i < 8; i++) ss += ra[i] * ra[i];
  ss = wsum(ss);
  float rms = rsqrtf(ss * (1.0f / DD) + 1e-6f);
  const float* wp = tn1 + lane * 8;
  float4 wa = *(const float4*)wp, wb = *(const float4*)(wp + 4);
  float wv8[8] = {wa.x, wa.y, wa.z, wa.w, wb.x, wb.y, wb.z, wb.w};
  float* np = nb + (size_t)wid * DD + lane * 8;
  float4 n0 = {ra[0]*rms*wv8[0], ra[1]*rms*wv8[1], ra[2]*rms*wv8[2], ra[3]*rms*wv8[3]};
  float4 n1 = {ra[4]*rms*wv8[4], ra[5]*rms*wv8[5], ra[6]*rms*wv8[6], ra[7]*rms*wv8[7]};
  *(float4*)np = n0;
  *(float4*)(np + 4) = n1;
}

__global__ void tree_combine_f(const float* __restrict__ g, const float* __restrict__ nb,
                               const float* __restrict__ sin_, const float* __restrict__ tn2,
                               float* __restrict__ sout, int Sn) {
  int wid = blockIdx.x * 4 + (threadIdx.x >> 6);
  int lane = threadIdx.x & 63;
  int rows = BB * Sn;
  if (wid >= rows) return;
  int b = wid / Sn, j = wid - b * Sn;
  const float* r0 = sin_ + ((size_t)(b * 2 * Sn + 2 * j)) * DD + lane * 8;
  const float* r1 = r0 + DD;
  float4 a0 = *(const float4*)r0, a1 = *(const float4*)(r0 + 4);
  float4 b0 = *(const float4*)r1, b1 = *(const float4*)(r1 + 4);
  float res[8] = {0.5f*(a0.x + b0.x), 0.5f*(a0.y + b0.y), 0.5f*(a0.z + b0.z), 0.5f*(a0.w + b0.w),
                  0.5f*(a1.x + b1.x), 0.5f*(a1.y + b1.y), 0.5f*(a1.z + b1.z), 0.5f*(a1.w + b1.w)};
  size_t base = (size_t)wid * DD + lane * 8;
  float t[8];
  float ss = 0.0f;
#pragma unroll
  for (int i = 0; i < 8; i++) {
    float gg = 1.0f / (1.0f + expf(-g[base + i]));
    float tv = gg * nb[base + i] + (1.0f - gg) * res[i];
    t[i] = tv;
    ss += tv * tv;
  }
  ss = wsum(ss);
  float rms = rsqrtf(ss * (1.0f / DD) + 1e-6f);
#pragma unroll
  for (int i = 0; i < 8; i++) sout[base + i] = t[i] * rms * tn2[lane * 8 + i];
}

// ======================= fused tree tail (levels 5..10), single block =======================
__global__ __launch_bounds__(1024) void tree_tail(float* __restrict__ s0,
                                                  float* __restrict__ s1,
                                                  const short* __restrict__ gwb,
                                                  const float* __restrict__ tn1,
                                                  const float* __restrict__ tn2) {
  __shared__ short nlds[64 * 512];
  __shared__ float rowsum[64];
  const int tid = threadIdx.x, w = tid >> 6, l = tid & 63;
  const int lg = l >> 4, ll = l & 15;
  const int wr = (w >> 3) * 32, wc = (w & 7) * 64;
  float* pin = s0;
  float* pout = s1;
  for (int lvl = 0; lvl < 6; lvl++) {
    const int Sn = 32 >> lvl;   // output rows per batch
    const int r2 = 2 * Sn;      // total output rows
    // ---- phase 1: pair-reduce + rmsnorm -> nlds (bf16, swizzled) ----
    {
      int r = tid >> 4;          // 0..63
      int c0 = (tid & 15) * 32;  // 32 cols per thread
      float ra[32];
      float ss = 0.0f;
      if (r < r2) {
        int b = (r >= Sn) ? 1 : 0;
        int j = r - b * Sn;
        const float* p0 = pin + ((size_t)(b * 2 * Sn + 2 * j)) * DD + c0;
        const float* p1 = p0 + DD;
#pragma unroll
        for (int i = 0; i < 8; i++) {
          float4 u = *(const float4*)(p0 + i * 4);
          float4 v = *(const float4*)(p1 + i * 4);
          ra[i*4+0] = u.x + v.x; ra[i*4+1] = u.y + v.y;
          ra[i*4+2] = u.z + v.z; ra[i*4+3] = u.w + v.w;
          ss += ra[i*4]*ra[i*4] + ra[i*4+1]*ra[i*4+1]
              + ra[i*4+2]*ra[i*4+2] + ra[i*4+3]*ra[i*4+3];
        }
      }
      ss += __shfl_xor(ss, 1); ss += __shfl_xor(ss, 2);
      ss += __shfl_xor(ss, 4); ss += __shfl_xor(ss, 8);
      float rms = rsqrtf(ss * (1.0f / DD) + 1e-6f);
#pragma unroll
      for (int gg = 0; gg < 4; gg++) {
        int g0 = (c0 >> 3) + gg;
        bf16x8 va;
#pragma unroll
        for (int e = 0; e < 8; e++) {
          float nv = (r < r2) ? (ra[gg*8+e] * rms * tn1[c0 + gg*8 + e]) : 0.0f;
          va[e] = f2b(nv);
        }
        *(bf16x8*)(nlds + r * 512 + ((g0 ^ (r & 7)) << 3)) = va;
      }
    }
    __syncthreads();
    // ---- phase 2: gate GEMM (M=64 padded, N=512, K=512) ----
    f32x4 acc[2][4] = {};
    for (int k0 = 0; k0 < 512; k0 += 32) {
      bf16x8 af[2], bfr[4];
#pragma unroll
      for (int m = 0; m < 2; m++) {
        int row = wr + m * 16 + ll;
        int g0 = (k0 >> 3) + lg;
        af[m] = *(const bf16x8*)(nlds + row * 512 + ((g0 ^ (row & 7)) << 3));
      }
#pragma unroll
      for (int n = 0; n < 4; n++) {
        int col = wc + n * 16 + ll;
        bfr[n] = *(const bf16x8*)(gwb + (size_t)col * 512 + k0 + lg * 8);
      }
#pragma unroll
      for (int m = 0; m < 2; m++)
#pragma unroll
        for (int n = 0; n < 4; n++)
          acc[m][n] = __builtin_amdgcn_mfma_f32_16x16x32_bf16(af[m], bfr[n], acc[m][n], 0, 0, 0);
    }
    // ---- phase 3: combine + rmsnorm ----
    __syncthreads();
    if (tid < 64) rowsum[tid] = 0.0f;
    __syncthreads();
    float tv[2][4][4];
#pragma unroll
    for (int m = 0; m < 2; m++)
#pragma unroll
      for (int j = 0; j < 4; j++) {
        int row = wr + m * 16 + lg * 4 + j;
        int b = (row >= Sn) ? 1 : 0;
        int ji = row - b * Sn;
        int in0 = b * 2 * Sn + 2 * ji;
        float part = 0.0f;
#pragma unroll
        for (int n = 0; n < 4; n++) {
          int col = wc + n * 16 + ll;
          float g = __builtin_amdgcn_rcpf(1.0f + __expf(-acc[m][n][j]));
          float nv = b2f(nlds[row * 512 + (((col >> 3) ^ (row & 7)) << 3) + (col & 7)]);
          float res = 0.5f * (pin[(size_t)in0 * DD + col] + pin[(size_t)(in0 + 1) * DD + col]);
          float t = g * nv + (1.0f - g) * res;
          tv[m][n][j] = t;
          part += t * t;
        }
        part += __shfl_xor(part, 1); part += __shfl_xor(part, 2);
        part += __shfl_xor(part, 4); part += __shfl_xor(part, 8);
        if (ll == 0 && row < r2) atomicAdd(&rowsum[row], part);
      }
    __syncthreads();
#pragma unroll
    for (int m = 0; m < 2; m++)
#pragma unroll
      for (int j = 0; j < 4; j++) {
        int row = wr + m * 16 + lg * 4 + j;
        if (row < r2) {
          float rms2 = rsqrtf(rowsum[row] * (1.0f / DD) + 1e-6f);
#pragma unroll
          for (int n = 0; n < 4; n++) {
            int col = wc + n * 16 + ll;
            pout[(size_t)row * DD + col] = tv[m][n][j] * rms2 * tn2[col];
          }
        }
      }
    __syncthreads();
    float* tmp = pin; pin = pout; pout = tmp;
  }
}

__global__ void h3hn_f(const float* __restrict__ h2, const float* __restrict__ root,
                       const float* __restrict__ fw, float* __restrict__ h3,
                       float* __restrict__ hn) {
  int wid = blockIdx.x * 4 + (threadIdx.x >> 6);
  int lane = threadIdx.x & 63;
  int b = wid >> 11;
  size_t base = (size_t)wid * DD + lane * 8;
  const float* rp = root + (size_t)b * DD + lane * 8;
  float t[8];
  float ss = 0.0f;
#pragma unroll
  for (int i = 0; i < 8; i++) {
    float tv = h2[base + i] + rp[i];
    t[i] = tv;
    ss += tv * tv;
    h3[base + i] = tv;
  }
  ss = wsum(ss);
  float rms = rsqrtf(ss * (1.0f / DD) + 1e-6f);
#pragma unroll
  for (int i = 0; i < 8; i++) hn[base + i] = t[i] * rms * fw[lane * 8 + i];
}

// ======================= upgate (single bf16) =======================
__global__ __launch_bounds__(256) void upgate_f(const float* __restrict__ A,
                                                const float* __restrict__ Bv,
                                                float* __restrict__ ffa) {
  __shared__ short Ah[128 * 32];
  __shared__ short B1h[128 * 32];
  __shared__ short B2h[128 * 32];
  const int tid = threadIdx.x, l = tid & 63, w = tid >> 6;
  const int wr = (w >> 1) * 64, wc = (w & 1) * 64;
  const int bm = blockIdx.y * 128, bn = blockIdx.x * 128;
  f32x4 acc1[4][4] = {}, acc2[4][4] = {};
  for (int k0 = 0; k0 < RANKK; k0 += 32) {
#pragma unroll
    for (int i = 0; i < 4; i++) {
      int lin = i * 256 + tid;
      int row = lin >> 3, f4 = lin & 7;
      float4 v = *(const float4*)(A + (size_t)(bm + row) * RANKK + k0 + f4 * 4);
      int off = row * 32 + (((f4 >> 1) ^ ((row >> 1) & 3)) << 3) + (f4 & 1) * 4;
      short4 hh;
      hh.x = f2b(v.x); hh.y = f2b(v.y); hh.z = f2b(v.z); hh.w = f2b(v.w);
      *(short4*)(Ah + off) = hh;
    }
#pragma unroll
    for (int i = 0; i < 4; i++) {
      int lin = i * 256 + tid;
      int kk = lin >> 5, f4n = lin & 31;
      float4 v1 = *(const float4*)(Bv + (size_t)(k0 + kk) * (2 * DFFF) + bn + f4n * 4);
      float4 v2 = *(const float4*)(Bv + (size_t)(k0 + kk) * (2 * DFFF) + DFFF + bn + f4n * 4);
      float a1[4] = {v1.x, v1.y, v1.z, v1.w};
      float a2[4] = {v2.x, v2.y, v2.z, v2.w};
#pragma unroll
      for (int e = 0; e < 4; e++) {
        int row = f4n * 4 + e;
        int off = row * 32 + (((kk >> 3) ^ ((row >> 1) & 3)) << 3) + (kk & 7);
        B1h[off] = f2b(a1[e]);
        B2h[off] = f2b(a2[e]);
      }
    }
    __syncthreads();
    bf16x8 ah[4], b1[4], b2[4];
#pragma unroll
    for (int m = 0; m < 4; m++) {
      int r = wr + m * 16 + (l & 15);
      int go = (((l >> 4) ^ ((r >> 1) & 3)) << 3);
      ah[m] = *(const bf16x8*)(Ah + r * 32 + go);
    }
#pragma unroll
    for (int n = 0; n < 4; n++) {
      int r = wc + n * 16 + (l & 15);
      int go = (((l >> 4) ^ ((r >> 1) & 3)) << 3);
      b1[n] = *(const bf16x8*)(B1h + r * 32 + go);
      b2[n] = *(const bf16x8*)(B2h + r * 32 + go);
    }
#pragma unroll
    for (int m = 0; m < 4; m++)
#pragma unroll
      for (int n = 0; n < 4; n++) {
        acc1[m][n] = __builtin_amdgcn_mfma_f32_16x16x32_bf16(ah[m], b1[n], acc1[m][n], 0, 0, 0);
        acc2[m][n] = __builtin_amdgcn_mfma_f32_16x16x32_bf16(ah[m], b2[n], acc2[m][n], 0, 0, 0);
      }
    __syncthreads();
  }
#pragma unroll
  for (int m = 0; m < 4; m++)
#pragma unroll
    for (int n = 0; n < 4; n++) {
      int gn = bn + wc + n * 16 + (l & 15);
#pragma unroll
      for (int j = 0; j < 4; j++) {
        int gm = bm + wr + m * 16 + (l >> 4) * 4 + j;
        float a = acc1[m][n][j];
        float s = a / (1.0f + __expf(-a));
        ffa[(size_t)gm * DFFF + gn] = s * acc2[m][n][j];
      }
    }
}

// ======================= launch =======================
extern "C" void kernel_launch(void* const* d_in, const int* in_sizes, int n_in,
                              void* d_out, int out_size, void* d_ws, size_t ws_size,
                              hipStream_t stream) {
  const float* x   = (const float*)d_in[0];
  const float* nw  = (const float*)d_in[1];
  const float* wq  = (const float*)d_in[2];
  const float* wk  = (const float*)d_in[3];
  const float* wv  = (const float*)d_in[4];
  const float* wo  = (const float*)d_in[5];
  const float* lat = (const float*)d_in[6];
  const float* btp = (const float*)d_in[7];
  const float* asw = (const float*)d_in[8];
  const float* gw  = (const float*)d_in[9];
  const float* tn1 = (const float*)d_in[10];
  const float* tn2 = (const float*)d_in[11];
  const float* fnw = (const float*)d_in[12];
  const float* uw  = (const float*)d_in[13];
  const float* vw  = (const float*)d_in[14];
  const float* dw  = (const float*)d_in[15];
  float* out = (float*)d_out;
  char* W = (char*)d_ws;

  float* fA = (float*)(W);
  float* fB = (float*)(W + (size_t)(8u << 20));
  float* fC = (float*)(W + (size_t)(16u << 20));
  float* fD = (float*)(W + (size_t)(24u << 20));
  float* fE = (float*)(W + (size_t)(32u << 20));
  short* gwb = (short*)(W + (size_t)(40u << 20));  // [512][512] bf16

  float* h = fA;
  float* q = fB;
  float* kbuf = fC;
  float* vT = fD;
  float* attn = fA;
  float* aprojT = fB;
  float* mixed = fC;
  float* h2 = fE;
  float* nb = fA;
  float* gb = fA + 1048576;
  float* s0 = fD;
  float* s1 = fD + 1048576;
  float* t1 = fD + 1572864;
  float* hn = fA;
  float* ffa = fB;

  const int rows = BB * SS;  // 4096

  cvtb<<<256, 256, 0, stream>>>(gw, gwb, DD * DD);

  tsa_rmsnorm<<<rows / 4, 256, 0, stream>>>(x, nw, h, rows);

  sgemm<0, true, false, 0><<<dim3(4, 32), 256, 0, stream>>>(h, wq, nullptr, q,
                                                            rows, DD, DD, 0, 0, 0);
  sgemm<0, true, false, 0><<<dim3(4, 32), 256, 0, stream>>>(h, wk, nullptr, kbuf,
                                                            rows, DD, DD, 0, 0, 0);
  sgemm<0, true, false, 1><<<dim3(4, 32), 256, 0, stream>>>(h, wv, nullptr, vT,
                                                            rows, DD, DD, 0, 0, 0);

  tsa_rope<<<(BB * SS * HH * 32) / 256, 256, 0, stream>>>(q, kbuf);

  attn_f<<<dim3(32, HH, BB), 256, 0, stream>>>(q, kbuf, vT, attn);

  sgemm<0, true, false, 2><<<dim3(4, 32), 256, 0, stream>>>(attn, wo, nullptr, aprojT,
                                                            rows, DD, DD, 0, 0, 0);

  sgemm<0, true, true, 0><<<dim3(4, 16, 2), 256, 0, stream>>>(
      lat, aprojT, nullptr, mixed, SS, DD, SS, 0, (long long)DD * SS, (long long)SS * DD);

  tsa_alif2<<<16, 64, 0, stream>>>(mixed, x, btp, asw, h2);

  const float* sin_ = h2;
  for (int lvl = 0; lvl < 5; lvl++) {
    int Sn = 1024 >> lvl;
    int r2 = BB * Sn;
    float* sout = (lvl & 1) ? s1 : s0;
    tree_reduce_f<<<(r2 + 3) / 4, 256, 0, stream>>>(sin_, tn1, nb, Sn);
    sgemm<0, false, false, 0><<<dim3(4, (r2 + 127) / 128), 256, 0, stream>>>(
        nb, gw, nullptr, gb, r2, DD, DD, 0, 0, 0);
    tree_combine_f<<<(r2 + 3) / 4, 256, 0, stream>>>(gb, nb, sin_, tn2, sout, Sn);
    sin_ = sout;
  }
  // levels 5..10 fused; input = s0 (lvl4 output), final root lands in s0
  tree_tail<<<1, 1024, 0, stream>>>(s0, s1, gwb, tn1, tn2);

  h3hn_f<<<rows / 4, 256, 0, stream>>>(h2, s0, fnw, out, hn);

  sgemm<1, false, false, 0><<<dim3(1, 32), 256, 0, stream>>>(hn, uw, nullptr, t1,
                                                             rows, RANKK, DD, 0, 0, 0);
  upgate_f<<<dim3(8, 32), 256, 0, stream>>>(t1, vw, ffa);
  sgemm<1, false, false, 3><<<dim3(4, 32), 256, 0, stream>>>(ffa, dw, out, out,
                                                             rows, DD, DFFF, 0, 0, 0);
}

// Round 5
// 996.926 us; speedup vs baseline: 1.1722x; 1.1722x over previous
//
#include <hip/hip_runtime.h>
#include <math.h>

#define BB 2
#define SS 2048
#define DD 512
#define HH 8
#define HDD 64
#define RANKK 128
#define DFFF 1024

typedef short bf16x8 __attribute__((ext_vector_type(8)));
typedef float f32x4 __attribute__((ext_vector_type(4)));

__device__ __forceinline__ short f2b(float f) {
  union { float f; unsigned u; } v; v.f = f;
  unsigned r = v.u + 0x7FFF + ((v.u >> 16) & 1);
  return (short)(r >> 16);
}
__device__ __forceinline__ float b2f(short s) {
  union { unsigned u; float f; } v; v.u = ((unsigned)(unsigned short)s) << 16;
  return v.f;
}

__device__ __forceinline__ float wsum(float v) {
#pragma unroll
  for (int off = 32; off > 0; off >>= 1) v += __shfl_xor(v, off, 64);
  return v;
}

// ---------------- rmsnorm fp32 ----------------
__global__ void tsa_rmsnorm(const float* __restrict__ x, const float* __restrict__ w,
                            float* __restrict__ o, int rows) {
  int wid = blockIdx.x * 4 + (threadIdx.x >> 6);
  int lane = threadIdx.x & 63;
  if (wid >= rows) return;
  const float* xp = x + (size_t)wid * DD + lane * 8;
  float4 a = *(const float4*)xp;
  float4 b = *(const float4*)(xp + 4);
  float ss = a.x*a.x + a.y*a.y + a.z*a.z + a.w*a.w
           + b.x*b.x + b.y*b.y + b.z*b.z + b.w*b.w;
  ss = wsum(ss);
  float r = rsqrtf(ss * (1.0f / DD) + 1e-6f);
  const float* wp = w + lane * 8;
  float4 wa = *(const float4*)wp, wb = *(const float4*)(wp + 4);
  float* op = o + (size_t)wid * DD + lane * 8;
  float4 oa = {a.x*r*wa.x, a.y*r*wa.y, a.z*r*wa.z, a.w*r*wa.w};
  float4 ob = {b.x*r*wb.x, b.y*r*wb.y, b.z*r*wb.z, b.w*r*wb.w};
  *(float4*)op = oa;
  *(float4*)(op + 4) = ob;
}

// ======================= split-precision GEMM =======================
// A fp32 [M][K]; B fp32 [N][K] (BL=0) or [K][N] (BL=1). C = A@B(^T).
// SPLIT: hi/lo bf16 decomposition (3-term MFMA). TRILA: mask A to k<=m.
// OM: 0 f32 [M][N]; 1 vT scatter; 2 aprojT scatter; 3 +=ADD.
// ROPE: apply rotate-half RoPE to the output tile (rows = seq, 64-col heads).
template <int BL, bool SPLIT, bool TRILA, int OM, bool ROPE>
__global__ __launch_bounds__(256) void sgemm(const float* __restrict__ A,
                                             const float* __restrict__ Bm,
                                             const float* __restrict__ ADD,
                                             float* __restrict__ C,
                                             int M, int N, int K,
                                             long long sA, long long sB, long long sC) {
  A += (long long)blockIdx.z * sA;
  Bm += (long long)blockIdx.z * sB;
  C += (long long)blockIdx.z * sC;
  __shared__ short Ah[128 * 32];
  __shared__ short Al[SPLIT ? 128 * 32 : 64];
  __shared__ short Bh[128 * 32];
  __shared__ short Bl[SPLIT ? 128 * 32 : 64];
  const int tid = threadIdx.x, l = tid & 63, w = tid >> 6;
  const int wr = (w >> 1) * 64, wc = (w & 1) * 64;
  const int bm = blockIdx.y * 128, bn = blockIdx.x * 128;
  f32x4 acc[4][4] = {};
  const int kend = TRILA ? min(K, bm + 128) : K;
  for (int k0 = 0; k0 < kend; k0 += 32) {
#pragma unroll
    for (int i = 0; i < 4; i++) {
      int lin = i * 256 + tid;
      int row = lin >> 3, f4 = lin & 7;
      int gr = min(bm + row, M - 1);
      float4 v = *(const float4*)(A + (size_t)gr * K + k0 + f4 * 4);
      if (TRILA) {
        int kc = k0 + f4 * 4;
        if (kc + 0 > gr) v.x = 0.0f;
        if (kc + 1 > gr) v.y = 0.0f;
        if (kc + 2 > gr) v.z = 0.0f;
        if (kc + 3 > gr) v.w = 0.0f;
      }
      int off = row * 32 + (((f4 >> 1) ^ ((row >> 1) & 3)) << 3) + (f4 & 1) * 4;
      short4 hh;
      hh.x = f2b(v.x); hh.y = f2b(v.y); hh.z = f2b(v.z); hh.w = f2b(v.w);
      *(short4*)(Ah + off) = hh;
      if (SPLIT) {
        short4 lo;
        lo.x = f2b(v.x - b2f(hh.x)); lo.y = f2b(v.y - b2f(hh.y));
        lo.z = f2b(v.z - b2f(hh.z)); lo.w = f2b(v.w - b2f(hh.w));
        *(short4*)(Al + off) = lo;
      }
    }
    if (BL == 0) {
#pragma unroll
      for (int i = 0; i < 4; i++) {
        int lin = i * 256 + tid;
        int row = lin >> 3, f4 = lin & 7;
        int gr = min(bn + row, N - 1);
        float4 v = *(const float4*)(Bm + (size_t)gr * K + k0 + f4 * 4);
        int off = row * 32 + (((f4 >> 1) ^ ((row >> 1) & 3)) << 3) + (f4 & 1) * 4;
        short4 hh;
        hh.x = f2b(v.x); hh.y = f2b(v.y); hh.z = f2b(v.z); hh.w = f2b(v.w);
        *(short4*)(Bh + off) = hh;
        if (SPLIT) {
          short4 lo;
          lo.x = f2b(v.x - b2f(hh.x)); lo.y = f2b(v.y - b2f(hh.y));
          lo.z = f2b(v.z - b2f(hh.z)); lo.w = f2b(v.w - b2f(hh.w));
          *(short4*)(Bl + off) = lo;
        }
      }
    } else {
#pragma unroll
      for (int i = 0; i < 4; i++) {
        int lin = i * 256 + tid;
        int kk = lin >> 5, f4n = lin & 31;
        float4 v = *(const float4*)(Bm + (size_t)(k0 + kk) * N + bn + f4n * 4);
        float vv[4] = {v.x, v.y, v.z, v.w};
#pragma unroll
        for (int e = 0; e < 4; e++) {
          int row = f4n * 4 + e;
          int off = row * 32 + (((kk >> 3) ^ ((row >> 1) & 3)) << 3) + (kk & 7);
          short hi = f2b(vv[e]);
          Bh[off] = hi;
          if (SPLIT) Bl[off] = f2b(vv[e] - b2f(hi));
        }
      }
    }
    __syncthreads();
    bf16x8 ah[4], bh[4], al_[4], bl_[4];
#pragma unroll
    for (int m = 0; m < 4; m++) {
      int r = wr + m * 16 + (l & 15);
      int go = (((l >> 4) ^ ((r >> 1) & 3)) << 3);
      ah[m] = *(const bf16x8*)(Ah + r * 32 + go);
      if (SPLIT) al_[m] = *(const bf16x8*)(Al + r * 32 + go);
    }
#pragma unroll
    for (int n = 0; n < 4; n++) {
      int r = wc + n * 16 + (l & 15);
      int go = (((l >> 4) ^ ((r >> 1) & 3)) << 3);
      bh[n] = *(const bf16x8*)(Bh + r * 32 + go);
      if (SPLIT) bl_[n] = *(const bf16x8*)(Bl + r * 32 + go);
    }
#pragma unroll
    for (int m = 0; m < 4; m++)
#pragma unroll
      for (int n = 0; n < 4; n++) {
        acc[m][n] = __builtin_amdgcn_mfma_f32_16x16x32_bf16(ah[m], bh[n], acc[m][n], 0, 0, 0);
        if (SPLIT) {
          acc[m][n] = __builtin_amdgcn_mfma_f32_16x16x32_bf16(ah[m], bl_[n], acc[m][n], 0, 0, 0);
          acc[m][n] = __builtin_amdgcn_mfma_f32_16x16x32_bf16(al_[m], bh[n], acc[m][n], 0, 0, 0);
        }
      }
    __syncthreads();
  }
  const int ll = l & 15, lg4 = (l >> 4) * 4;
  if (ROPE) {
    // cols (bn+wc aligned to 64): head-local i = n*16+ll for n in {0,1};
    // partner col i+32 lives in fragment n+2. rows: s = gm & (SS-1).
#pragma unroll
    for (int m = 0; m < 4; m++)
#pragma unroll
      for (int n = 0; n < 2; n++) {
        int i_ = n * 16 + ll;
        float inv = exp2f(-(float)i_ * (13.287712379549449f / 32.0f));
#pragma unroll
        for (int j = 0; j < 4; j++) {
          int gm = bm + wr + m * 16 + lg4 + j;
          int s = gm & (SS - 1);
          float ang = (float)s * inv;
          float sn, cs;
          sincosf(ang, &sn, &cs);
          float v1 = acc[m][n][j], v2 = acc[m][n + 2][j];
          acc[m][n][j]     = v1 * cs - v2 * sn;
          acc[m][n + 2][j] = v2 * cs + v1 * sn;
        }
      }
  }
#pragma unroll
  for (int m = 0; m < 4; m++)
#pragma unroll
    for (int n = 0; n < 4; n++) {
      int gn = bn + wc + n * 16 + ll;
#pragma unroll
      for (int j = 0; j < 4; j++) {
        int gm = bm + wr + m * 16 + lg4 + j;
        if (gm >= M || gn >= N) continue;
        float v = acc[m][n][j];
        if (OM == 0) {
          C[(size_t)gm * N + gn] = v;
        } else if (OM == 1) {
          int b = gm >> 11, s2 = gm & (SS - 1);
          int hh2 = gn >> 6, d = gn & 63;
          C[(((size_t)(b * HH + hh2)) * HDD + d) * SS + s2] = v;
        } else if (OM == 2) {
          int b = gm >> 11, s2 = gm & (SS - 1);
          C[((size_t)b * DD + gn) * SS + s2] = v;
        } else {
          size_t off = (size_t)gm * N + gn;
          C[off] = v + ADD[off];
        }
      }
    }
}

// ======================= split-precision flash attention =======================
__global__ __launch_bounds__(256) void attn_f(const float* __restrict__ q,
                                              const float* __restrict__ k,
                                              const float* __restrict__ vT,
                                              float* __restrict__ attn) {
  const int h = blockIdx.y, b = blockIdx.z;
  const int q0 = blockIdx.x * 64;
  const int tid = threadIdx.x, w = tid >> 6, l = tid & 63;
  const int lg = l >> 4, ll = l & 15;
  __shared__ short Kh[64 * 64], Kl[64 * 64];
  __shared__ short Vh[64 * 64], Vl[64 * 64];
  __shared__ short Ph[64 * 64], Pl[64 * 64];

#pragma unroll
  for (int i = 0; i < 4; i++) {
    int lin = i * 256 + tid;
    int row = lin >> 4, f4 = lin & 15;
    float4 v = *(const float4*)(q + ((size_t)(b * SS + q0 + row)) * DD + h * HDD + f4 * 4);
    int off = row * 64 + (((f4 >> 1) ^ (row & 7)) << 3) + (f4 & 1) * 4;
    short4 hh, lo;
    hh.x = f2b(v.x); hh.y = f2b(v.y); hh.z = f2b(v.z); hh.w = f2b(v.w);
    lo.x = f2b(v.x - b2f(hh.x)); lo.y = f2b(v.y - b2f(hh.y));
    lo.z = f2b(v.z - b2f(hh.z)); lo.w = f2b(v.w - b2f(hh.w));
    *(short4*)(Ph + off) = hh;
    *(short4*)(Pl + off) = lo;
  }
  __syncthreads();
  bf16x8 qfh[2], qfl[2];
  {
    int qr = w * 16 + ll;
#pragma unroll
    for (int ks = 0; ks < 2; ks++) {
      int g = (ks * 4 + lg) ^ (qr & 7);
      qfh[ks] = *(const bf16x8*)(Ph + qr * 64 + g * 8);
      qfl[ks] = *(const bf16x8*)(Pl + qr * 64 + g * 8);
    }
  }
  __syncthreads();

  f32x4 o[4] = {};
  float mrow[4] = {-1e30f, -1e30f, -1e30f, -1e30f};
  float lsum[4] = {};
  const int qrow0 = q0 + w * 16 + lg * 4;
  const int ntiles = blockIdx.x + 1;

  for (int kt = 0; kt < ntiles; kt++) {
#pragma unroll
    for (int i = 0; i < 4; i++) {
      int lin = i * 256 + tid;
      int row = lin >> 4, f4 = lin & 15;
      int off = row * 64 + (((f4 >> 1) ^ (row & 7)) << 3) + (f4 & 1) * 4;
      float4 kv = *(const float4*)(k + ((size_t)(b * SS + kt * 64 + row)) * DD + h * HDD + f4 * 4);
      short4 hh, lo;
      hh.x = f2b(kv.x); hh.y = f2b(kv.y); hh.z = f2b(kv.z); hh.w = f2b(kv.w);
      lo.x = f2b(kv.x - b2f(hh.x)); lo.y = f2b(kv.y - b2f(hh.y));
      lo.z = f2b(kv.z - b2f(hh.z)); lo.w = f2b(kv.w - b2f(hh.w));
      *(short4*)(Kh + off) = hh;
      *(short4*)(Kl + off) = lo;
      float4 vv = *(const float4*)(vT + (((size_t)(b * HH + h)) * HDD + row) * SS + kt * 64 + f4 * 4);
      hh.x = f2b(vv.x); hh.y = f2b(vv.y); hh.z = f2b(vv.z); hh.w = f2b(vv.w);
      lo.x = f2b(vv.x - b2f(hh.x)); lo.y = f2b(vv.y - b2f(hh.y));
      lo.z = f2b(vv.z - b2f(hh.z)); lo.w = f2b(vv.w - b2f(hh.w));
      *(short4*)(Vh + off) = hh;
      *(short4*)(Vl + off) = lo;
    }
    __syncthreads();

    f32x4 sv[4] = {};
#pragma unroll
    for (int nf = 0; nf < 4; nf++) {
      int r = nf * 16 + ll;
#pragma unroll
      for (int ks = 0; ks < 2; ks++) {
        int g = (ks * 4 + lg) ^ (r & 7);
        bf16x8 kh = *(const bf16x8*)(Kh + r * 64 + g * 8);
        bf16x8 kl = *(const bf16x8*)(Kl + r * 64 + g * 8);
        sv[nf] = __builtin_amdgcn_mfma_f32_16x16x32_bf16(qfh[ks], kh, sv[nf], 0, 0, 0);
        sv[nf] = __builtin_amdgcn_mfma_f32_16x16x32_bf16(qfh[ks], kl, sv[nf], 0, 0, 0);
        sv[nf] = __builtin_amdgcn_mfma_f32_16x16x32_bf16(qfl[ks], kh, sv[nf], 0, 0, 0);
      }
    }
#pragma unroll
    for (int nf = 0; nf < 4; nf++) {
      int kpos = kt * 64 + nf * 16 + ll;
#pragma unroll
      for (int j = 0; j < 4; j++) {
        float v = sv[nf][j] * 0.125f;
        sv[nf][j] = (kpos > qrow0 + j) ? -1e30f : v;
      }
    }
    float cf[4];
#pragma unroll
    for (int j = 0; j < 4; j++) {
      float r = fmaxf(fmaxf(sv[0][j], sv[1][j]), fmaxf(sv[2][j], sv[3][j]));
      r = fmaxf(r, __shfl_xor(r, 1)); r = fmaxf(r, __shfl_xor(r, 2));
      r = fmaxf(r, __shfl_xor(r, 4)); r = fmaxf(r, __shfl_xor(r, 8));
      float mn = fmaxf(mrow[j], r);
      cf[j] = __expf(mrow[j] - mn);
      mrow[j] = mn;
    }
    float ps[4] = {};
#pragma unroll
    for (int nf = 0; nf < 4; nf++)
#pragma unroll
      for (int j = 0; j < 4; j++) {
        float p = __expf(sv[nf][j] - mrow[j]);
        sv[nf][j] = p;
        ps[j] += p;
      }
#pragma unroll
    for (int j = 0; j < 4; j++) {
      float r = ps[j];
      r += __shfl_xor(r, 1); r += __shfl_xor(r, 2);
      r += __shfl_xor(r, 4); r += __shfl_xor(r, 8);
      lsum[j] = lsum[j] * cf[j] + r;
    }
#pragma unroll
    for (int nf = 0; nf < 4; nf++)
#pragma unroll
      for (int j = 0; j < 4; j++) o[nf][j] *= cf[j];
#pragma unroll
    for (int nf = 0; nf < 4; nf++)
#pragma unroll
      for (int j = 0; j < 4; j++) {
        int rowP = w * 16 + lg * 4 + j;
        int col = nf * 16 + ll;
        int off = rowP * 64 + (((col >> 3) ^ (rowP & 7)) << 3) + (col & 7);
        float p = sv[nf][j];
        short hi = f2b(p);
        Ph[off] = hi;
        Pl[off] = f2b(p - b2f(hi));
      }
    __syncthreads();
    bf16x8 pfh[2], pfl[2];
    {
      int rowA = w * 16 + ll;
#pragma unroll
      for (int ks = 0; ks < 2; ks++) {
        int g = (ks * 4 + lg) ^ (rowA & 7);
        pfh[ks] = *(const bf16x8*)(Ph + rowA * 64 + g * 8);
        pfl[ks] = *(const bf16x8*)(Pl + rowA * 64 + g * 8);
      }
    }
#pragma unroll
    for (int nf = 0; nf < 4; nf++) {
      int r = nf * 16 + ll;
#pragma unroll
      for (int ks = 0; ks < 2; ks++) {
        int g = (ks * 4 + lg) ^ (r & 7);
        bf16x8 vh = *(const bf16x8*)(Vh + r * 64 + g * 8);
        bf16x8 vl = *(const bf16x8*)(Vl + r * 64 + g * 8);
        o[nf] = __builtin_amdgcn_mfma_f32_16x16x32_bf16(pfh[ks], vh, o[nf], 0, 0, 0);
        o[nf] = __builtin_amdgcn_mfma_f32_16x16x32_bf16(pfh[ks], vl, o[nf], 0, 0, 0);
        o[nf] = __builtin_amdgcn_mfma_f32_16x16x32_bf16(pfl[ks], vh, o[nf], 0, 0, 0);
      }
    }
    __syncthreads();
  }
  float inv[4];
#pragma unroll
  for (int j = 0; j < 4; j++) inv[j] = 1.0f / lsum[j];
#pragma unroll
  for (int nf = 0; nf < 4; nf++)
#pragma unroll
    for (int j = 0; j < 4; j++)
      attn[((size_t)(b * SS + qrow0 + j)) * DD + h * HDD + nf * 16 + ll] = o[nf][j] * inv[j];
}

// ======================= ALIF scan: deep prefetch + fast sigmoid =======================
#define ACH 32
__global__ __launch_bounds__(64) void tsa_alif2(const float* __restrict__ mixed,
                                                const float* __restrict__ x,
                                                const float* __restrict__ bt,
                                                const float* __restrict__ asw,
                                                float* __restrict__ h2) {
  int tid = blockIdx.x * 64 + threadIdx.x;  // 16 blocks x 64
  int b = tid >> 9, d = tid & 511;
  const float btd = bt[d], asd = asw[d];
  const float* mp = mixed + (size_t)b * SS * DD + d;
  const float* xp = x + (size_t)b * SS * DD + d;
  float* hp = h2 + (size_t)b * SS * DD + d;
  float vmem = 0.0f, ad = 0.0f;
  float mA[ACH], xA[ACH], mB[ACH], xB[ACH];
#pragma unroll
  for (int j = 0; j < ACH; j++) {
    mA[j] = mp[(size_t)j * DD];
    xA[j] = xp[(size_t)j * DD];
  }
  for (int t0 = 0; t0 < SS; t0 += 2 * ACH) {
#pragma unroll
    for (int j = 0; j < ACH; j++) {
      mB[j] = mp[(size_t)(t0 + ACH + j) * DD];
      xB[j] = xp[(size_t)(t0 + ACH + j) * DD];
    }
#pragma unroll
    for (int j = 0; j < ACH; j++) {
      float m = mA[j];
      vmem = fmaf(0.99f, vmem, m);
      float th = fmaf(asd, ad, btd);
      float e = __expf(-25.0f * (vmem - th));
      float s = __builtin_amdgcn_rcpf(1.0f + e);
      vmem -= s * th;
      ad = fmaf(0.95f, ad, s);
      hp[(size_t)(t0 + j) * DD] = xA[j] + m + s;
    }
    if (t0 + 2 * ACH < SS) {
#pragma unroll
      for (int j = 0; j < ACH; j++) {
        mA[j] = mp[(size_t)(t0 + 2 * ACH + j) * DD];
        xA[j] = xp[(size_t)(t0 + 2 * ACH + j) * DD];
      }
    }
#pragma unroll
    for (int j = 0; j < ACH; j++) {
      float m = mB[j];
      vmem = fmaf(0.99f, vmem, m);
      float th = fmaf(asd, ad, btd);
      float e = __expf(-25.0f * (vmem - th));
      float s = __builtin_amdgcn_rcpf(1.0f + e);
      vmem -= s * th;
      ad = fmaf(0.95f, ad, s);
      hp[(size_t)(t0 + ACH + j) * DD] = xB[j] + m + s;
    }
  }
}

// ======================= tree kernels (fp32) =======================
__global__ void tree_reduce_f(const float* __restrict__ sin_, const float* __restrict__ tn1,
                              float* __restrict__ nb, int Sn) {
  int wid = blockIdx.x * 4 + (threadIdx.x >> 6);
  int lane = threadIdx.x & 63;
  int rows = BB * Sn;
  if (wid >= rows) return;
  int b = wid / Sn, j = wid - b * Sn;
  const float* r0 = sin_ + ((size_t)(b * 2 * Sn + 2 * j)) * DD + lane * 8;
  const float* r1 = r0 + DD;
  float4 a0 = *(const float4*)r0, a1 = *(const float4*)(r0 + 4);
  float4 b0 = *(const float4*)r1, b1 = *(const float4*)(r1 + 4);
  float ra[8] = {a0.x + b0.x, a0.y + b0.y, a0.z + b0.z, a0.w + b0.w,
                 a1.x + b1.x, a1.y + b1.y, a1.z + b1.z, a1.w + b1.w};
  float ss = 0.0f;
#pragma unroll
  for (int i = 0; i < 8; i++) ss += ra[i] * ra[i];
  ss = wsum(ss);
  float rms = rsqrtf(ss * (1.0f / DD) + 1e-6f);
  const float* wp = tn1 + lane * 8;
  float4 wa = *(const float4*)wp, wb = *(const float4*)(wp + 4);
  float wv8[8] = {wa.x, wa.y, wa.z, wa.w, wb.x, wb.y, wb.z, wb.w};
  float* np = nb + (size_t)wid * DD + lane * 8;
  float4 n0 = {ra[0]*rms*wv8[0], ra[1]*rms*wv8[1], ra[2]*rms*wv8[2], ra[3]*rms*wv8[3]};
  float4 n1 = {ra[4]*rms*wv8[4], ra[5]*rms*wv8[5], ra[6]*rms*wv8[6], ra[7]*rms*wv8[7]};
  *(float4*)np = n0;
  *(float4*)(np + 4) = n1;
}

__global__ void tree_combine_f(const float* __restrict__ g, const float* __restrict__ nb,
                               const float* __restrict__ sin_, const float* __restrict__ tn2,
                               float* __restrict__ sout, int Sn) {
  int wid = blockIdx.x * 4 + (threadIdx.x >> 6);
  int lane = threadIdx.x & 63;
  int rows = BB * Sn;
  if (wid >= rows) return;
  int b = wid / Sn, j = wid - b * Sn;
  const float* r0 = sin_ + ((size_t)(b * 2 * Sn + 2 * j)) * DD + lane * 8;
  const float* r1 = r0 + DD;
  float4 a0 = *(const float4*)r0, a1 = *(const float4*)(r0 + 4);
  float4 b0 = *(const float4*)r1, b1 = *(const float4*)(r1 + 4);
  float res[8] = {0.5f*(a0.x + b0.x), 0.5f*(a0.y + b0.y), 0.5f*(a0.z + b0.z), 0.5f*(a0.w + b0.w),
                  0.5f*(a1.x + b1.x), 0.5f*(a1.y + b1.y), 0.5f*(a1.z + b1.z), 0.5f*(a1.w + b1.w)};
  size_t base = (size_t)wid * DD + lane * 8;
  float t[8];
  float ss = 0.0f;
#pragma unroll
  for (int i = 0; i < 8; i++) {
    float gg = 1.0f / (1.0f + expf(-g[base + i]));
    float tv = gg * nb[base + i] + (1.0f - gg) * res[i];
    t[i] = tv;
    ss += tv * tv;
  }
  ss = wsum(ss);
  float rms = rsqrtf(ss * (1.0f / DD) + 1e-6f);
#pragma unroll
  for (int i = 0; i < 8; i++) sout[base + i] = t[i] * rms * tn2[lane * 8 + i];
}

__global__ void h3hn_f(const float* __restrict__ h2, const float* __restrict__ root,
                       const float* __restrict__ fw, float* __restrict__ h3,
                       float* __restrict__ hn) {
  int wid = blockIdx.x * 4 + (threadIdx.x >> 6);
  int lane = threadIdx.x & 63;
  int b = wid >> 11;
  size_t base = (size_t)wid * DD + lane * 8;
  const float* rp = root + (size_t)b * DD + lane * 8;
  float t[8];
  float ss = 0.0f;
#pragma unroll
  for (int i = 0; i < 8; i++) {
    float tv = h2[base + i] + rp[i];
    t[i] = tv;
    ss += tv * tv;
    h3[base + i] = tv;
  }
  ss = wsum(ss);
  float rms = rsqrtf(ss * (1.0f / DD) + 1e-6f);
#pragma unroll
  for (int i = 0; i < 8; i++) hn[base + i] = t[i] * rms * fw[lane * 8 + i];
}

// ======================= upgate (single bf16) =======================
__global__ __launch_bounds__(256) void upgate_f(const float* __restrict__ A,
                                                const float* __restrict__ Bv,
                                                float* __restrict__ ffa) {
  __shared__ short Ah[128 * 32];
  __shared__ short B1h[128 * 32];
  __shared__ short B2h[128 * 32];
  const int tid = threadIdx.x, l = tid & 63, w = tid >> 6;
  const int wr = (w >> 1) * 64, wc = (w & 1) * 64;
  const int bm = blockIdx.y * 128, bn = blockIdx.x * 128;
  f32x4 acc1[4][4] = {}, acc2[4][4] = {};
  for (int k0 = 0; k0 < RANKK; k0 += 32) {
#pragma unroll
    for (int i = 0; i < 4; i++) {
      int lin = i * 256 + tid;
      int row = lin >> 3, f4 = lin & 7;
      float4 v = *(const float4*)(A + (size_t)(bm + row) * RANKK + k0 + f4 * 4);
      int off = row * 32 + (((f4 >> 1) ^ ((row >> 1) & 3)) << 3) + (f4 & 1) * 4;
      short4 hh;
      hh.x = f2b(v.x); hh.y = f2b(v.y); hh.z = f2b(v.z); hh.w = f2b(v.w);
      *(short4*)(Ah + off) = hh;
    }
#pragma unroll
    for (int i = 0; i < 4; i++) {
      int lin = i * 256 + tid;
      int kk = lin >> 5, f4n = lin & 31;
      float4 v1 = *(const float4*)(Bv + (size_t)(k0 + kk) * (2 * DFFF) + bn + f4n * 4);
      float4 v2 = *(const float4*)(Bv + (size_t)(k0 + kk) * (2 * DFFF) + DFFF + bn + f4n * 4);
      float a1[4] = {v1.x, v1.y, v1.z, v1.w};
      float a2[4] = {v2.x, v2.y, v2.z, v2.w};
#pragma unroll
      for (int e = 0; e < 4; e++) {
        int row = f4n * 4 + e;
        int off = row * 32 + (((kk >> 3) ^ ((row >> 1) & 3)) << 3) + (kk & 7);
        B1h[off] = f2b(a1[e]);
        B2h[off] = f2b(a2[e]);
      }
    }
    __syncthreads();
    bf16x8 ah[4], b1[4], b2[4];
#pragma unroll
    for (int m = 0; m < 4; m++) {
      int r = wr + m * 16 + (l & 15);
      int go = (((l >> 4) ^ ((r >> 1) & 3)) << 3);
      ah[m] = *(const bf16x8*)(Ah + r * 32 + go);
    }
#pragma unroll
    for (int n = 0; n < 4; n++) {
      int r = wc + n * 16 + (l & 15);
      int go = (((l >> 4) ^ ((r >> 1) & 3)) << 3);
      b1[n] = *(const bf16x8*)(B1h + r * 32 + go);
      b2[n] = *(const bf16x8*)(B2h + r * 32 + go);
    }
#pragma unroll
    for (int m = 0; m < 4; m++)
#pragma unroll
      for (int n = 0; n < 4; n++) {
        acc1[m][n] = __builtin_amdgcn_mfma_f32_16x16x32_bf16(ah[m], b1[n], acc1[m][n], 0, 0, 0);
        acc2[m][n] = __builtin_amdgcn_mfma_f32_16x16x32_bf16(ah[m], b2[n], acc2[m][n], 0, 0, 0);
      }
    __syncthreads();
  }
#pragma unroll
  for (int m = 0; m < 4; m++)
#pragma unroll
    for (int n = 0; n < 4; n++) {
      int gn = bn + wc + n * 16 + (l & 15);
#pragma unroll
      for (int j = 0; j < 4; j++) {
        int gm = bm + wr + m * 16 + (l >> 4) * 4 + j;
        float a = acc1[m][n][j];
        float s = a / (1.0f + __expf(-a));
        ffa[(size_t)gm * DFFF + gn] = s * acc2[m][n][j];
      }
    }
}

// ======================= launch =======================
extern "C" void kernel_launch(void* const* d_in, const int* in_sizes, int n_in,
                              void* d_out, int out_size, void* d_ws, size_t ws_size,
                              hipStream_t stream) {
  const float* x   = (const float*)d_in[0];
  const float* nw  = (const float*)d_in[1];
  const float* wq  = (const float*)d_in[2];
  const float* wk  = (const float*)d_in[3];
  const float* wv  = (const float*)d_in[4];
  const float* wo  = (const float*)d_in[5];
  const float* lat = (const float*)d_in[6];
  const float* btp = (const float*)d_in[7];
  const float* asw = (const float*)d_in[8];
  const float* gw  = (const float*)d_in[9];
  const float* tn1 = (const float*)d_in[10];
  const float* tn2 = (const float*)d_in[11];
  const float* fnw = (const float*)d_in[12];
  const float* uw  = (const float*)d_in[13];
  const float* vw  = (const float*)d_in[14];
  const float* dw  = (const float*)d_in[15];
  float* out = (float*)d_out;
  char* W = (char*)d_ws;

  float* fA = (float*)(W);
  float* fB = (float*)(W + (size_t)(8u << 20));
  float* fC = (float*)(W + (size_t)(16u << 20));
  float* fD = (float*)(W + (size_t)(24u << 20));
  float* fE = (float*)(W + (size_t)(32u << 20));

  float* h = fA;
  float* q = fB;
  float* kbuf = fC;
  float* vT = fD;
  float* attn = fA;
  float* aprojT = fB;
  float* mixed = fC;
  float* h2 = fE;
  float* nb = fA;
  float* gb = fA + 1048576;
  float* s0 = fD;
  float* s1 = fD + 1048576;
  float* t1 = fD + 1572864;
  float* hn = fA;
  float* ffa = fB;

  const int rows = BB * SS;  // 4096

  tsa_rmsnorm<<<rows / 4, 256, 0, stream>>>(x, nw, h, rows);

  // QKV with fused RoPE on q,k
  sgemm<0, true, false, 0, true><<<dim3(4, 32), 256, 0, stream>>>(h, wq, nullptr, q,
                                                                  rows, DD, DD, 0, 0, 0);
  sgemm<0, true, false, 0, true><<<dim3(4, 32), 256, 0, stream>>>(h, wk, nullptr, kbuf,
                                                                  rows, DD, DD, 0, 0, 0);
  sgemm<0, true, false, 1, false><<<dim3(4, 32), 256, 0, stream>>>(h, wv, nullptr, vT,
                                                                   rows, DD, DD, 0, 0, 0);

  attn_f<<<dim3(32, HH, BB), 256, 0, stream>>>(q, kbuf, vT, attn);

  sgemm<0, true, false, 2, false><<<dim3(4, 32), 256, 0, stream>>>(attn, wo, nullptr, aprojT,
                                                                   rows, DD, DD, 0, 0, 0);

  sgemm<0, true, true, 0, false><<<dim3(4, 16, 2), 256, 0, stream>>>(
      lat, aprojT, nullptr, mixed, SS, DD, SS, 0, (long long)DD * SS, (long long)SS * DD);

  tsa_alif2<<<16, 64, 0, stream>>>(mixed, x, btp, asw, h2);

  const float* sin_ = h2;
  for (int lvl = 0; lvl < 11; lvl++) {
    int Sn = 1024 >> lvl;
    int r2 = BB * Sn;
    float* sout = (lvl & 1) ? s1 : s0;
    tree_reduce_f<<<(r2 + 3) / 4, 256, 0, stream>>>(sin_, tn1, nb, Sn);
    sgemm<0, false, false, 0, false><<<dim3(4, (r2 + 127) / 128), 256, 0, stream>>>(
        nb, gw, nullptr, gb, r2, DD, DD, 0, 0, 0);
    tree_combine_f<<<(r2 + 3) / 4, 256, 0, stream>>>(gb, nb, sin_, tn2, sout, Sn);
    sin_ = sout;
  }

  h3hn_f<<<rows / 4, 256, 0, stream>>>(h2, sin_, fnw, out, hn);

  sgemm<1, false, false, 0, false><<<dim3(1, 32), 256, 0, stream>>>(hn, uw, nullptr, t1,
                                                                    rows, RANKK, DD, 0, 0, 0);
  upgate_f<<<dim3(8, 32), 256, 0, stream>>>(t1, vw, ffa);
  sgemm<1, false, false, 3, false><<<dim3(4, 32), 256, 0, stream>>>(ffa, dw, out, out,
                                                                    rows, DD, DFFF, 0, 0, 0);
}

// Round 6
// 806.705 us; speedup vs baseline: 1.4487x; 1.2358x over previous
//
#include <hip/hip_runtime.h>
#include <math.h>

#define BB 2
#define SS 2048
#define DD 512
#define HH 8
#define HDD 64
#define RANKK 128
#define DFFF 1024

typedef short bf16x8 __attribute__((ext_vector_type(8)));
typedef float f32x4 __attribute__((ext_vector_type(4)));

__device__ __forceinline__ short f2b(float f) {
  union { float f; unsigned u; } v; v.f = f;
  unsigned r = v.u + 0x7FFF + ((v.u >> 16) & 1);
  return (short)(r >> 16);
}
__device__ __forceinline__ float b2f(short s) {
  union { unsigned u; float f; } v; v.u = ((unsigned)(unsigned short)s) << 16;
  return v.f;
}

__device__ __forceinline__ void gll16(const void* g, void* l) {
  __builtin_amdgcn_global_load_lds(
      (const __attribute__((address_space(1))) unsigned int*)g,
      (__attribute__((address_space(3))) unsigned int*)l, 16, 0, 0);
}

__device__ __forceinline__ float wsum(float v) {
#pragma unroll
  for (int off = 32; off > 0; off >>= 1) v += __shfl_xor(v, off, 64);
  return v;
}

// ---------------- weight split fp32 -> hi/lo bf16 ----------------
__global__ void splitw(const float* __restrict__ in, short* __restrict__ hi,
                       short* __restrict__ lo, int n) {
  int i = (blockIdx.x * 256 + threadIdx.x) * 4;
  if (i >= n) return;
  float4 v = *(const float4*)(in + i);
  short4 h4, l4;
  h4.x = f2b(v.x); l4.x = f2b(v.x - b2f(h4.x));
  h4.y = f2b(v.y); l4.y = f2b(v.y - b2f(h4.y));
  h4.z = f2b(v.z); l4.z = f2b(v.z - b2f(h4.z));
  h4.w = f2b(v.w); l4.w = f2b(v.w - b2f(h4.w));
  *(short4*)(hi + i) = h4;
  *(short4*)(lo + i) = l4;
}

// ---------------- fp32 -> bf16 single ----------------
__global__ void cvtb(const float* __restrict__ in, short* __restrict__ out, int n) {
  int i = (blockIdx.x * 256 + threadIdx.x) * 4;
  if (i >= n) return;
  float4 v = *(const float4*)(in + i);
  short4 o; o.x = f2b(v.x); o.y = f2b(v.y); o.z = f2b(v.z); o.w = f2b(v.w);
  *(short4*)(out + i) = o;
}

// ---------------- transpose + convert: in f32 [R][C] -> out bf16 [C][R] ----------------
__global__ void transp_cvt(const float* __restrict__ in, short* __restrict__ out,
                           int R, int C) {
  __shared__ float t[32][33];
  int c0 = blockIdx.x * 32, r0 = blockIdx.y * 32;
#pragma unroll
  for (int i = 0; i < 4; i++) {
    int idx = threadIdx.x + i * 256;
    int r = idx >> 5, c = idx & 31;
    t[r][c] = in[(size_t)(r0 + r) * C + c0 + c];
  }
  __syncthreads();
#pragma unroll
  for (int i = 0; i < 4; i++) {
    int idx = threadIdx.x + i * 256;
    int cc = idx >> 5, rr = idx & 31;
    out[(size_t)(c0 + cc) * R + r0 + rr] = f2b(t[rr][cc]);
  }
}

// ---------------- rmsnorm fp32 -> split bf16 ----------------
__global__ void rmsnorm_hl(const float* __restrict__ x, const float* __restrict__ w,
                           short* __restrict__ oh, short* __restrict__ ol, int rows) {
  int wid = blockIdx.x * 4 + (threadIdx.x >> 6);
  int lane = threadIdx.x & 63;
  if (wid >= rows) return;
  const float* xp = x + (size_t)wid * DD + lane * 8;
  float4 a = *(const float4*)xp;
  float4 b = *(const float4*)(xp + 4);
  float ss = a.x*a.x + a.y*a.y + a.z*a.z + a.w*a.w
           + b.x*b.x + b.y*b.y + b.z*b.z + b.w*b.w;
  ss = wsum(ss);
  float r = rsqrtf(ss * (1.0f / DD) + 1e-6f);
  const float* wp = w + lane * 8;
  float4 wa = *(const float4*)wp, wb = *(const float4*)(wp + 4);
  float o8[8] = {a.x*r*wa.x, a.y*r*wa.y, a.z*r*wa.z, a.w*r*wa.w,
                 b.x*r*wb.x, b.y*r*wb.y, b.z*r*wb.z, b.w*r*wb.w};
  short hv[8], lv[8];
#pragma unroll
  for (int i = 0; i < 8; i++) { hv[i] = f2b(o8[i]); lv[i] = f2b(o8[i] - b2f(hv[i])); }
  short* op = oh + (size_t)wid * DD + lane * 8;
  short* lp = ol + (size_t)wid * DD + lane * 8;
  *(short4*)op = make_short4(hv[0], hv[1], hv[2], hv[3]);
  *(short4*)(op + 4) = make_short4(hv[4], hv[5], hv[6], hv[7]);
  *(short4*)lp = make_short4(lv[0], lv[1], lv[2], lv[3]);
  *(short4*)(lp + 4) = make_short4(lv[4], lv[5], lv[6], lv[7]);
}

// ======================= unified bf16 GEMM, gll16 staging =======================
// A bf16 [M][K] (hi +lo if SPL), B bf16 [N][K] (hi +lo if SPL). C = A@B^T.
// OM: 0 fp32 [M][N]; 1 bf16 [M][N]; 2 qk split scatter (+ROPE); 3 vT split scatter;
//     4 aprojT split scatter; 6 fp32 +=ADD.
template <bool SPL, int OM, bool ROPE>
__global__ __launch_bounds__(256) void ggemm(const short* __restrict__ Ah_g,
                                             const short* __restrict__ Al_g,
                                             const short* __restrict__ Bh_g,
                                             const short* __restrict__ Bl_g,
                                             const float* __restrict__ ADD,
                                             void* __restrict__ C, void* __restrict__ C2,
                                             int M, int N, int K) {
  __shared__ short Ahs[128 * 32];
  __shared__ short Bhs[128 * 32];
  __shared__ short Als[SPL ? 128 * 32 : 8];
  __shared__ short Bls[SPL ? 128 * 32 : 8];
  const int tid = threadIdx.x, l = tid & 63, w = tid >> 6;
  const int wr = (w >> 1) * 64, wc = (w & 1) * 64;
  const int bm = blockIdx.y * 128, bn = blockIdx.x * 128;
  f32x4 acc[4][4] = {};
  for (int k0 = 0; k0 < K; k0 += 32) {
#pragma unroll
    for (int p = 0; p < 2; p++) {
      int row = p * 64 + (tid >> 2), g = tid & 3;
      int swz = (g ^ ((row >> 1) & 3)) * 8;
      gll16(Ah_g + (size_t)(bm + row) * K + k0 + swz, Ahs + p * 2048 + tid * 8);
      gll16(Bh_g + (size_t)(bn + row) * K + k0 + swz, Bhs + p * 2048 + tid * 8);
      if (SPL) {
        gll16(Al_g + (size_t)(bm + row) * K + k0 + swz, Als + p * 2048 + tid * 8);
        gll16(Bl_g + (size_t)(bn + row) * K + k0 + swz, Bls + p * 2048 + tid * 8);
      }
    }
    __syncthreads();
    bf16x8 ah[4], bh[4], al[4], bl[4];
#pragma unroll
    for (int m = 0; m < 4; m++) {
      int r = wr + m * 16 + (l & 15);
      int go = (((l >> 4) ^ ((r >> 1) & 3)) << 3);
      ah[m] = *(const bf16x8*)(Ahs + r * 32 + go);
      if (SPL) al[m] = *(const bf16x8*)(Als + r * 32 + go);
    }
#pragma unroll
    for (int n = 0; n < 4; n++) {
      int r = wc + n * 16 + (l & 15);
      int go = (((l >> 4) ^ ((r >> 1) & 3)) << 3);
      bh[n] = *(const bf16x8*)(Bhs + r * 32 + go);
      if (SPL) bl[n] = *(const bf16x8*)(Bls + r * 32 + go);
    }
#pragma unroll
    for (int m = 0; m < 4; m++)
#pragma unroll
      for (int n = 0; n < 4; n++) {
        acc[m][n] = __builtin_amdgcn_mfma_f32_16x16x32_bf16(ah[m], bh[n], acc[m][n], 0, 0, 0);
        if (SPL) {
          acc[m][n] = __builtin_amdgcn_mfma_f32_16x16x32_bf16(ah[m], bl[n], acc[m][n], 0, 0, 0);
          acc[m][n] = __builtin_amdgcn_mfma_f32_16x16x32_bf16(al[m], bh[n], acc[m][n], 0, 0, 0);
        }
      }
    __syncthreads();
  }
  const int ll = l & 15, lg4 = (l >> 4) * 4;
  if (ROPE) {
#pragma unroll
    for (int m = 0; m < 4; m++)
#pragma unroll
      for (int n = 0; n < 2; n++) {
        int i_ = n * 16 + ll;
        float inv = exp2f(-(float)i_ * (13.287712379549449f / 32.0f));
#pragma unroll
        for (int j = 0; j < 4; j++) {
          int gm = bm + wr + m * 16 + lg4 + j;
          int s = gm & (SS - 1);
          float ang = (float)s * inv;
          float sn, cs;
          sincosf(ang, &sn, &cs);
          float v1 = acc[m][n][j], v2 = acc[m][n + 2][j];
          acc[m][n][j]     = v1 * cs - v2 * sn;
          acc[m][n + 2][j] = v2 * cs + v1 * sn;
        }
      }
  }
#pragma unroll
  for (int m = 0; m < 4; m++)
#pragma unroll
    for (int n = 0; n < 4; n++) {
      int gn = bn + wc + n * 16 + ll;
#pragma unroll
      for (int j = 0; j < 4; j++) {
        int gm = bm + wr + m * 16 + lg4 + j;
        if (gm >= M || gn >= N) continue;
        float v = acc[m][n][j];
        if (OM == 0) {
          ((float*)C)[(size_t)gm * N + gn] = v;
        } else if (OM == 1) {
          ((short*)C)[(size_t)gm * N + gn] = f2b(v);
        } else if (OM == 6) {
          size_t off = (size_t)gm * N + gn;
          ((float*)C)[off] = v + ADD[off];
        } else {
          short hi = f2b(v);
          short lo = f2b(v - b2f(hi));
          int b = gm >> 11, s = gm & (SS - 1);
          int hh2 = gn >> 6, d = gn & 63;
          size_t off;
          if (OM == 2)      off = (((size_t)(b * HH + hh2)) * SS + s) * 64 + d;
          else if (OM == 3) off = (((size_t)(b * HH + hh2)) * 64 + d) * SS + s;
          else              off = ((size_t)(b * DD) + gn) * SS + s;
          ((short*)C)[off] = hi;
          ((short*)C2)[off] = lo;
        }
      }
    }
}

// ======================= lateral GEMM: masked fp32 A (reg-split), split B via gll16 =======================
__global__ __launch_bounds__(256) void lat_g(const float* __restrict__ lat,
                                             const short* __restrict__ bTh,
                                             const short* __restrict__ bTl,
                                             float* __restrict__ Cc) {
  int z = blockIdx.z;
  bTh += (size_t)z * DD * SS;
  bTl += (size_t)z * DD * SS;
  Cc += (size_t)z * SS * DD;
  __shared__ short Ah[128 * 32];
  __shared__ short Al[128 * 32];
  __shared__ short Bh[128 * 32];
  __shared__ short Bl[128 * 32];
  const int tid = threadIdx.x, l = tid & 63, w = tid >> 6;
  const int wr = (w >> 1) * 64, wc = (w & 1) * 64;
  const int bm = blockIdx.y * 128, bn = blockIdx.x * 128;
  f32x4 acc[4][4] = {};
  const int kend = bm + 128;
  for (int k0 = 0; k0 < kend; k0 += 32) {
#pragma unroll
    for (int p = 0; p < 2; p++) {
      int row = p * 64 + (tid >> 2), g = tid & 3;
      int swz = (g ^ ((row >> 1) & 3)) * 8;
      gll16(bTh + (size_t)(bn + row) * SS + k0 + swz, Bh + p * 2048 + tid * 8);
      gll16(bTl + (size_t)(bn + row) * SS + k0 + swz, Bl + p * 2048 + tid * 8);
    }
#pragma unroll
    for (int i = 0; i < 4; i++) {
      int lin = i * 256 + tid;
      int row = lin >> 3, f4 = lin & 7;
      int gr = bm + row;
      float4 v = *(const float4*)(lat + (size_t)gr * SS + k0 + f4 * 4);
      int kc = k0 + f4 * 4;
      if (kc + 0 > gr) v.x = 0.0f;
      if (kc + 1 > gr) v.y = 0.0f;
      if (kc + 2 > gr) v.z = 0.0f;
      if (kc + 3 > gr) v.w = 0.0f;
      int off = row * 32 + (((f4 >> 1) ^ ((row >> 1) & 3)) << 3) + (f4 & 1) * 4;
      short4 hh, lo;
      hh.x = f2b(v.x); lo.x = f2b(v.x - b2f(hh.x));
      hh.y = f2b(v.y); lo.y = f2b(v.y - b2f(hh.y));
      hh.z = f2b(v.z); lo.z = f2b(v.z - b2f(hh.z));
      hh.w = f2b(v.w); lo.w = f2b(v.w - b2f(hh.w));
      *(short4*)(Ah + off) = hh;
      *(short4*)(Al + off) = lo;
    }
    __syncthreads();
    bf16x8 ah[4], bh[4], al[4], bl[4];
#pragma unroll
    for (int m = 0; m < 4; m++) {
      int r = wr + m * 16 + (l & 15);
      int go = (((l >> 4) ^ ((r >> 1) & 3)) << 3);
      ah[m] = *(const bf16x8*)(Ah + r * 32 + go);
      al[m] = *(const bf16x8*)(Al + r * 32 + go);
    }
#pragma unroll
    for (int n = 0; n < 4; n++) {
      int r = wc + n * 16 + (l & 15);
      int go = (((l >> 4) ^ ((r >> 1) & 3)) << 3);
      bh[n] = *(const bf16x8*)(Bh + r * 32 + go);
      bl[n] = *(const bf16x8*)(Bl + r * 32 + go);
    }
#pragma unroll
    for (int m = 0; m < 4; m++)
#pragma unroll
      for (int n = 0; n < 4; n++) {
        acc[m][n] = __builtin_amdgcn_mfma_f32_16x16x32_bf16(ah[m], bh[n], acc[m][n], 0, 0, 0);
        acc[m][n] = __builtin_amdgcn_mfma_f32_16x16x32_bf16(ah[m], bl[n], acc[m][n], 0, 0, 0);
        acc[m][n] = __builtin_amdgcn_mfma_f32_16x16x32_bf16(al[m], bh[n], acc[m][n], 0, 0, 0);
      }
    __syncthreads();
  }
  const int ll = l & 15, lg4 = (l >> 4) * 4;
#pragma unroll
  for (int m = 0; m < 4; m++)
#pragma unroll
    for (int n = 0; n < 4; n++) {
      int gn = bn + wc + n * 16 + ll;
#pragma unroll
      for (int j = 0; j < 4; j++) {
        int gm = bm + wr + m * 16 + lg4 + j;
        Cc[(size_t)gm * DD + gn] = acc[m][n][j];
      }
    }
}

// ======================= flash attention, split bf16 in/out, gll16 staging =======================
__global__ __launch_bounds__(256) void attn_g(const short* __restrict__ qh,
                                              const short* __restrict__ ql,
                                              const short* __restrict__ kh,
                                              const short* __restrict__ kl,
                                              const short* __restrict__ vh,
                                              const short* __restrict__ vl,
                                              short* __restrict__ aho,
                                              short* __restrict__ alo) {
  const int h = blockIdx.y, b = blockIdx.z;
  const int q0 = blockIdx.x * 64;
  const int tid = threadIdx.x, w = tid >> 6, l = tid & 63;
  const int lg = l >> 4, ll = l & 15;
  __shared__ short Kh[64 * 64], Kl[64 * 64];
  __shared__ short Vh[64 * 64], Vl[64 * 64];
  __shared__ short Ph[64 * 64], Pl[64 * 64];
  const size_t bh = (size_t)(b * HH + h);

  // Q fragments straight from global
  const int qr = q0 + w * 16 + ll;
  const short* qbh = qh + (bh * SS + qr) * 64;
  const short* qbl = ql + (bh * SS + qr) * 64;
  bf16x8 qfh[2], qfl[2];
#pragma unroll
  for (int ks = 0; ks < 2; ks++) {
    qfh[ks] = *(const bf16x8*)(qbh + (ks * 4 + lg) * 8);
    qfl[ks] = *(const bf16x8*)(qbl + (ks * 4 + lg) * 8);
  }

  f32x4 o[4] = {};
  float mrow[4] = {-1e30f, -1e30f, -1e30f, -1e30f};
  float lsum[4] = {};
  const int qrow0 = q0 + w * 16 + lg * 4;
  const int ntiles = blockIdx.x + 1;

  for (int kt = 0; kt < ntiles; kt++) {
#pragma unroll
    for (int p = 0; p < 2; p++) {
      int row = p * 32 + (tid >> 3), g = tid & 7;
      int sw = ((g ^ (row & 7)) << 3);
      size_t krow = (bh * SS + kt * 64 + row) * 64;
      size_t vrow = (bh * 64 + row) * SS + kt * 64;
      gll16(kh + krow + sw, Kh + p * 2048 + tid * 8);
      gll16(kl + krow + sw, Kl + p * 2048 + tid * 8);
      gll16(vh + vrow + sw, Vh + p * 2048 + tid * 8);
      gll16(vl + vrow + sw, Vl + p * 2048 + tid * 8);
    }
    __syncthreads();

    f32x4 sv[4] = {};
#pragma unroll
    for (int nf = 0; nf < 4; nf++) {
      int r = nf * 16 + ll;
#pragma unroll
      for (int ks = 0; ks < 2; ks++) {
        int g = (ks * 4 + lg) ^ (r & 7);
        bf16x8 khf = *(const bf16x8*)(Kh + r * 64 + g * 8);
        bf16x8 klf = *(const bf16x8*)(Kl + r * 64 + g * 8);
        sv[nf] = __builtin_amdgcn_mfma_f32_16x16x32_bf16(qfh[ks], khf, sv[nf], 0, 0, 0);
        sv[nf] = __builtin_amdgcn_mfma_f32_16x16x32_bf16(qfh[ks], klf, sv[nf], 0, 0, 0);
        sv[nf] = __builtin_amdgcn_mfma_f32_16x16x32_bf16(qfl[ks], khf, sv[nf], 0, 0, 0);
      }
    }
#pragma unroll
    for (int nf = 0; nf < 4; nf++) {
      int kpos = kt * 64 + nf * 16 + ll;
#pragma unroll
      for (int j = 0; j < 4; j++) {
        float v = sv[nf][j] * 0.125f;
        sv[nf][j] = (kpos > qrow0 + j) ? -1e30f : v;
      }
    }
    float cf[4];
#pragma unroll
    for (int j = 0; j < 4; j++) {
      float r = fmaxf(fmaxf(sv[0][j], sv[1][j]), fmaxf(sv[2][j], sv[3][j]));
      r = fmaxf(r, __shfl_xor(r, 1)); r = fmaxf(r, __shfl_xor(r, 2));
      r = fmaxf(r, __shfl_xor(r, 4)); r = fmaxf(r, __shfl_xor(r, 8));
      float mn = fmaxf(mrow[j], r);
      cf[j] = __expf(mrow[j] - mn);
      mrow[j] = mn;
    }
    float ps[4] = {};
#pragma unroll
    for (int nf = 0; nf < 4; nf++)
#pragma unroll
      for (int j = 0; j < 4; j++) {
        float p = __expf(sv[nf][j] - mrow[j]);
        sv[nf][j] = p;
        ps[j] += p;
      }
#pragma unroll
    for (int j = 0; j < 4; j++) {
      float r = ps[j];
      r += __shfl_xor(r, 1); r += __shfl_xor(r, 2);
      r += __shfl_xor(r, 4); r += __shfl_xor(r, 8);
      lsum[j] = lsum[j] * cf[j] + r;
    }
#pragma unroll
    for (int nf = 0; nf < 4; nf++)
#pragma unroll
      for (int j = 0; j < 4; j++) o[nf][j] *= cf[j];
#pragma unroll
    for (int nf = 0; nf < 4; nf++)
#pragma unroll
      for (int j = 0; j < 4; j++) {
        int rowP = w * 16 + lg * 4 + j;
        int col = nf * 16 + ll;
        int off = rowP * 64 + (((col >> 3) ^ (rowP & 7)) << 3) + (col & 7);
        float p = sv[nf][j];
        short hi = f2b(p);
        Ph[off] = hi;
        Pl[off] = f2b(p - b2f(hi));
      }
    __syncthreads();
    bf16x8 pfh[2], pfl[2];
    {
      int rowA = w * 16 + ll;
#pragma unroll
      for (int ks = 0; ks < 2; ks++) {
        int g = (ks * 4 + lg) ^ (rowA & 7);
        pfh[ks] = *(const bf16x8*)(Ph + rowA * 64 + g * 8);
        pfl[ks] = *(const bf16x8*)(Pl + rowA * 64 + g * 8);
      }
    }
#pragma unroll
    for (int nf = 0; nf < 4; nf++) {
      int r = nf * 16 + ll;
#pragma unroll
      for (int ks = 0; ks < 2; ks++) {
        int g = (ks * 4 + lg) ^ (r & 7);
        bf16x8 vhf = *(const bf16x8*)(Vh + r * 64 + g * 8);
        bf16x8 vlf = *(const bf16x8*)(Vl + r * 64 + g * 8);
        o[nf] = __builtin_amdgcn_mfma_f32_16x16x32_bf16(pfh[ks], vhf, o[nf], 0, 0, 0);
        o[nf] = __builtin_amdgcn_mfma_f32_16x16x32_bf16(pfh[ks], vlf, o[nf], 0, 0, 0);
        o[nf] = __builtin_amdgcn_mfma_f32_16x16x32_bf16(pfl[ks], vhf, o[nf], 0, 0, 0);
      }
    }
    __syncthreads();
  }
  float inv[4];
#pragma unroll
  for (int j = 0; j < 4; j++) inv[j] = 1.0f / lsum[j];
#pragma unroll
  for (int nf = 0; nf < 4; nf++)
#pragma unroll
    for (int j = 0; j < 4; j++) {
      float v = o[nf][j] * inv[j];
      short hi = f2b(v);
      size_t off = ((size_t)(b * SS + qrow0 + j)) * DD + h * HDD + nf * 16 + ll;
      aho[off] = hi;
      alo[off] = f2b(v - b2f(hi));
    }
}

// ======================= ALIF scan: deep prefetch + fast sigmoid =======================
#define ACH 32
__global__ __launch_bounds__(64) void tsa_alif2(const float* __restrict__ mixed,
                                                const float* __restrict__ x,
                                                const float* __restrict__ bt,
                                                const float* __restrict__ asw,
                                                float* __restrict__ h2) {
  int tid = blockIdx.x * 64 + threadIdx.x;
  int b = tid >> 9, d = tid & 511;
  const float btd = bt[d], asd = asw[d];
  const float* mp = mixed + (size_t)b * SS * DD + d;
  const float* xp = x + (size_t)b * SS * DD + d;
  float* hp = h2 + (size_t)b * SS * DD + d;
  float vmem = 0.0f, ad = 0.0f;
  float mA[ACH], xA[ACH], mB[ACH], xB[ACH];
#pragma unroll
  for (int j = 0; j < ACH; j++) {
    mA[j] = mp[(size_t)j * DD];
    xA[j] = xp[(size_t)j * DD];
  }
  for (int t0 = 0; t0 < SS; t0 += 2 * ACH) {
#pragma unroll
    for (int j = 0; j < ACH; j++) {
      mB[j] = mp[(size_t)(t0 + ACH + j) * DD];
      xB[j] = xp[(size_t)(t0 + ACH + j) * DD];
    }
#pragma unroll
    for (int j = 0; j < ACH; j++) {
      float m = mA[j];
      vmem = fmaf(0.99f, vmem, m);
      float th = fmaf(asd, ad, btd);
      float e = __expf(-25.0f * (vmem - th));
      float s = __builtin_amdgcn_rcpf(1.0f + e);
      vmem -= s * th;
      ad = fmaf(0.95f, ad, s);
      hp[(size_t)(t0 + j) * DD] = xA[j] + m + s;
    }
    if (t0 + 2 * ACH < SS) {
#pragma unroll
      for (int j = 0; j < ACH; j++) {
        mA[j] = mp[(size_t)(t0 + 2 * ACH + j) * DD];
        xA[j] = xp[(size_t)(t0 + 2 * ACH + j) * DD];
      }
    }
#pragma unroll
    for (int j = 0; j < ACH; j++) {
      float m = mB[j];
      vmem = fmaf(0.99f, vmem, m);
      float th = fmaf(asd, ad, btd);
      float e = __expf(-25.0f * (vmem - th));
      float s = __builtin_amdgcn_rcpf(1.0f + e);
      vmem -= s * th;
      ad = fmaf(0.95f, ad, s);
      hp[(size_t)(t0 + ACH + j) * DD] = xB[j] + m + s;
    }
  }
}

// ======================= tree kernels =======================
__global__ void tree_reduce_b(const float* __restrict__ sin_, const float* __restrict__ tn1,
                              short* __restrict__ nb, int Sn) {
  int wid = blockIdx.x * 4 + (threadIdx.x >> 6);
  int lane = threadIdx.x & 63;
  int rows = BB * Sn;
  if (wid >= rows) return;
  int b = wid / Sn, j = wid - b * Sn;
  const float* r0 = sin_ + ((size_t)(b * 2 * Sn + 2 * j)) * DD + lane * 8;
  const float* r1 = r0 + DD;
  float4 a0 = *(const float4*)r0, a1 = *(const float4*)(r0 + 4);
  float4 b0 = *(const float4*)r1, b1 = *(const float4*)(r1 + 4);
  float ra[8] = {a0.x + b0.x, a0.y + b0.y, a0.z + b0.z, a0.w + b0.w,
                 a1.x + b1.x, a1.y + b1.y, a1.z + b1.z, a1.w + b1.w};
  float ss = 0.0f;
#pragma unroll
  for (int i = 0; i < 8; i++) ss += ra[i] * ra[i];
  ss = wsum(ss);
  float rms = rsqrtf(ss * (1.0f / DD) + 1e-6f);
  const float* wp = tn1 + lane * 8;
  float4 wa = *(const float4*)wp, wb = *(const float4*)(wp + 4);
  float wv8[8] = {wa.x, wa.y, wa.z, wa.w, wb.x, wb.y, wb.z, wb.w};
  short* np = nb + (size_t)wid * DD + lane * 8;
  short4 n0, n1;
  n0.x = f2b(ra[0]*rms*wv8[0]); n0.y = f2b(ra[1]*rms*wv8[1]);
  n0.z = f2b(ra[2]*rms*wv8[2]); n0.w = f2b(ra[3]*rms*wv8[3]);
  n1.x = f2b(ra[4]*rms*wv8[4]); n1.y = f2b(ra[5]*rms*wv8[5]);
  n1.z = f2b(ra[6]*rms*wv8[6]); n1.w = f2b(ra[7]*rms*wv8[7]);
  *(short4*)np = n0;
  *(short4*)(np + 4) = n1;
}

__global__ void tree_combine_b(const float* __restrict__ g, const short* __restrict__ nb,
                               const float* __restrict__ sin_, const float* __restrict__ tn2,
                               float* __restrict__ sout, int Sn) {
  int wid = blockIdx.x * 4 + (threadIdx.x >> 6);
  int lane = threadIdx.x & 63;
  int rows = BB * Sn;
  if (wid >= rows) return;
  int b = wid / Sn, j = wid - b * Sn;
  const float* r0 = sin_ + ((size_t)(b * 2 * Sn + 2 * j)) * DD + lane * 8;
  const float* r1 = r0 + DD;
  float4 a0 = *(const float4*)r0, a1 = *(const float4*)(r0 + 4);
  float4 b0 = *(const float4*)r1, b1 = *(const float4*)(r1 + 4);
  float res[8] = {0.5f*(a0.x + b0.x), 0.5f*(a0.y + b0.y), 0.5f*(a0.z + b0.z), 0.5f*(a0.w + b0.w),
                  0.5f*(a1.x + b1.x), 0.5f*(a1.y + b1.y), 0.5f*(a1.z + b1.z), 0.5f*(a1.w + b1.w)};
  size_t base = (size_t)wid * DD + lane * 8;
  float t[8];
  float ss = 0.0f;
#pragma unroll
  for (int i = 0; i < 8; i++) {
    float gg = 1.0f / (1.0f + expf(-g[base + i]));
    float tv = gg * b2f(nb[base + i]) + (1.0f - gg) * res[i];
    t[i] = tv;
    ss += tv * tv;
  }
  ss = wsum(ss);
  float rms = rsqrtf(ss * (1.0f / DD) + 1e-6f);
#pragma unroll
  for (int i = 0; i < 8; i++) sout[base + i] = t[i] * rms * tn2[lane * 8 + i];
}

// h3 = h2 + root -> out fp32; hn = rmsnorm(h3) -> bf16
__global__ void h3hn_b(const float* __restrict__ h2, const float* __restrict__ root,
                       const float* __restrict__ fw, float* __restrict__ h3,
                       short* __restrict__ hn) {
  int wid = blockIdx.x * 4 + (threadIdx.x >> 6);
  int lane = threadIdx.x & 63;
  int b = wid >> 11;
  size_t base = (size_t)wid * DD + lane * 8;
  const float* rp = root + (size_t)b * DD + lane * 8;
  float t[8];
  float ss = 0.0f;
#pragma unroll
  for (int i = 0; i < 8; i++) {
    float tv = h2[base + i] + rp[i];
    t[i] = tv;
    ss += tv * tv;
    h3[base + i] = tv;
  }
  ss = wsum(ss);
  float rms = rsqrtf(ss * (1.0f / DD) + 1e-6f);
#pragma unroll
  for (int i = 0; i < 8; i++) hn[base + i] = f2b(t[i] * rms * fw[lane * 8 + i]);
}

// ======================= upgate: bf16 A,B via gll16, silu fuse =======================
__global__ __launch_bounds__(256) void upgate_g(const short* __restrict__ A,
                                                const short* __restrict__ Bv,
                                                short* __restrict__ ffa) {
  __shared__ short Ahs[128 * 32];
  __shared__ short B1s[128 * 32];
  __shared__ short B2s[128 * 32];
  const int tid = threadIdx.x, l = tid & 63, w = tid >> 6;
  const int wr = (w >> 1) * 64, wc = (w & 1) * 64;
  const int bm = blockIdx.y * 128, bn = blockIdx.x * 128;
  f32x4 acc1[4][4] = {}, acc2[4][4] = {};
  for (int k0 = 0; k0 < RANKK; k0 += 32) {
#pragma unroll
    for (int p = 0; p < 2; p++) {
      int row = p * 64 + (tid >> 2), g = tid & 3;
      int swz = (g ^ ((row >> 1) & 3)) * 8;
      gll16(A + (size_t)(bm + row) * RANKK + k0 + swz, Ahs + p * 2048 + tid * 8);
      gll16(Bv + (size_t)(bn + row) * RANKK + k0 + swz, B1s + p * 2048 + tid * 8);
      gll16(Bv + (size_t)(DFFF + bn + row) * RANKK + k0 + swz, B2s + p * 2048 + tid * 8);
    }
    __syncthreads();
    bf16x8 ah[4], b1[4], b2[4];
#pragma unroll
    for (int m = 0; m < 4; m++) {
      int r = wr + m * 16 + (l & 15);
      int go = (((l >> 4) ^ ((r >> 1) & 3)) << 3);
      ah[m] = *(const bf16x8*)(Ahs + r * 32 + go);
    }
#pragma unroll
    for (int n = 0; n < 4; n++) {
      int r = wc + n * 16 + (l & 15);
      int go = (((l >> 4) ^ ((r >> 1) & 3)) << 3);
      b1[n] = *(const bf16x8*)(B1s + r * 32 + go);
      b2[n] = *(const bf16x8*)(B2s + r * 32 + go);
    }
#pragma unroll
    for (int m = 0; m < 4; m++)
#pragma unroll
      for (int n = 0; n < 4; n++) {
        acc1[m][n] = __builtin_amdgcn_mfma_f32_16x16x32_bf16(ah[m], b1[n], acc1[m][n], 0, 0, 0);
        acc2[m][n] = __builtin_amdgcn_mfma_f32_16x16x32_bf16(ah[m], b2[n], acc2[m][n], 0, 0, 0);
      }
    __syncthreads();
  }
#pragma unroll
  for (int m = 0; m < 4; m++)
#pragma unroll
    for (int n = 0; n < 4; n++) {
      int gn = bn + wc + n * 16 + (l & 15);
#pragma unroll
      for (int j = 0; j < 4; j++) {
        int gm = bm + wr + m * 16 + (l >> 4) * 4 + j;
        float a = acc1[m][n][j];
        float s = a / (1.0f + __expf(-a));
        ffa[(size_t)gm * DFFF + gn] = f2b(s * acc2[m][n][j]);
      }
    }
}

// ======================= launch =======================
extern "C" void kernel_launch(void* const* d_in, const int* in_sizes, int n_in,
                              void* d_out, int out_size, void* d_ws, size_t ws_size,
                              hipStream_t stream) {
  const float* x   = (const float*)d_in[0];
  const float* nw  = (const float*)d_in[1];
  const float* wq  = (const float*)d_in[2];
  const float* wk  = (const float*)d_in[3];
  const float* wv  = (const float*)d_in[4];
  const float* wo  = (const float*)d_in[5];
  const float* lat = (const float*)d_in[6];
  const float* btp = (const float*)d_in[7];
  const float* asw = (const float*)d_in[8];
  const float* gw  = (const float*)d_in[9];
  const float* tn1 = (const float*)d_in[10];
  const float* tn2 = (const float*)d_in[11];
  const float* fnw = (const float*)d_in[12];
  const float* uw  = (const float*)d_in[13];
  const float* vw  = (const float*)d_in[14];
  const float* dw  = (const float*)d_in[15];
  float* out = (float*)d_out;
  char* W = (char*)d_ws;
  const size_t MB = 1u << 20;

  // region 0-8MB
  short* h_hi = (short*)(W);
  short* h_lo = (short*)(W + 4 * MB);
  short* attn_hi = h_hi;
  short* attn_lo = h_lo;
  short* nb = (short*)(W);
  float* gb = (float*)(W + 2 * MB);
  // region 8-16MB
  short* q_hi = (short*)(W + 8 * MB);
  short* q_lo = (short*)(W + 12 * MB);
  short* apT_hi = q_hi;
  short* apT_lo = q_lo;
  float* s0 = (float*)(W + 8 * MB);
  float* s1 = (float*)(W + 12 * MB);
  // region 16-24MB
  short* k_hi = (short*)(W + 16 * MB);
  short* k_lo = (short*)(W + 20 * MB);
  short* hn = (short*)(W + 16 * MB);
  short* t1 = (short*)(W + 20 * MB);
  // region 24-32MB
  short* v_hi = (short*)(W + 24 * MB);
  short* v_lo = (short*)(W + 28 * MB);
  float* h2 = (float*)(W + 24 * MB);
  short* ffa = (short*)(W + 24 * MB);
  // region 32-40MB
  float* mixed = (float*)(W + 32 * MB);
  short* gwb = (short*)(W + 32 * MB);
  short* uwT = gwb + 262144;
  short* vwT = uwT + 65536;
  short* dwT = vwT + 262144;

  // split weights parked in d_out (dead before h3 is written)
  short* wqh = (short*)out;
  short* wql = wqh + 262144;
  short* wkh = wql + 262144;
  short* wkl = wkh + 262144;
  short* wvh = wkl + 262144;
  short* wvl = wvh + 262144;
  short* woh = wvl + 262144;
  short* wol = woh + 262144;

  const int rows = BB * SS;  // 4096

  splitw<<<256, 256, 0, stream>>>(wq, wqh, wql, DD * DD);
  splitw<<<256, 256, 0, stream>>>(wk, wkh, wkl, DD * DD);
  splitw<<<256, 256, 0, stream>>>(wv, wvh, wvl, DD * DD);
  splitw<<<256, 256, 0, stream>>>(wo, woh, wol, DD * DD);

  rmsnorm_hl<<<rows / 4, 256, 0, stream>>>(x, nw, h_hi, h_lo, rows);

  // QKV (RoPE fused on q,k)
  ggemm<true, 2, true><<<dim3(4, 32), 256, 0, stream>>>(
      h_hi, h_lo, wqh, wql, nullptr, q_hi, q_lo, rows, DD, DD);
  ggemm<true, 2, true><<<dim3(4, 32), 256, 0, stream>>>(
      h_hi, h_lo, wkh, wkl, nullptr, k_hi, k_lo, rows, DD, DD);
  ggemm<true, 3, false><<<dim3(4, 32), 256, 0, stream>>>(
      h_hi, h_lo, wvh, wvl, nullptr, v_hi, v_lo, rows, DD, DD);

  attn_g<<<dim3(32, HH, BB), 256, 0, stream>>>(q_hi, q_lo, k_hi, k_lo, v_hi, v_lo,
                                               attn_hi, attn_lo);

  ggemm<true, 4, false><<<dim3(4, 32), 256, 0, stream>>>(
      attn_hi, attn_lo, woh, wol, nullptr, apT_hi, apT_lo, rows, DD, DD);

  lat_g<<<dim3(4, 16, 2), 256, 0, stream>>>(lat, apT_hi, apT_lo, mixed);

  tsa_alif2<<<16, 64, 0, stream>>>(mixed, x, btp, asw, h2);

  // small weights (into dead mixed region)
  cvtb<<<256, 256, 0, stream>>>(gw, gwb, DD * DD);
  transp_cvt<<<dim3(4, 16), 256, 0, stream>>>(uw, uwT, DD, RANKK);
  transp_cvt<<<dim3(64, 4), 256, 0, stream>>>(vw, vwT, RANKK, 2 * DFFF);
  transp_cvt<<<dim3(16, 32), 256, 0, stream>>>(dw, dwT, DFFF, DD);

  const float* sin_ = h2;
  for (int lvl = 0; lvl < 11; lvl++) {
    int Sn = 1024 >> lvl;
    int r2 = BB * Sn;
    float* sout = (lvl & 1) ? s1 : s0;
    tree_reduce_b<<<(r2 + 3) / 4, 256, 0, stream>>>(sin_, tn1, nb, Sn);
    ggemm<false, 0, false><<<dim3(4, (r2 + 127) / 128), 256, 0, stream>>>(
        nb, nullptr, gwb, nullptr, nullptr, gb, nullptr, r2, DD, DD);
    tree_combine_b<<<(r2 + 3) / 4, 256, 0, stream>>>(gb, nb, sin_, tn2, sout, Sn);
    sin_ = sout;
  }

  h3hn_b<<<rows / 4, 256, 0, stream>>>(h2, sin_, fnw, out, hn);

  ggemm<false, 1, false><<<dim3(1, 32), 256, 0, stream>>>(
      hn, nullptr, uwT, nullptr, nullptr, t1, nullptr, rows, RANKK, DD);
  upgate_g<<<dim3(8, 32), 256, 0, stream>>>(t1, vwT, ffa);
  ggemm<false, 6, false><<<dim3(4, 32), 256, 0, stream>>>(
      ffa, nullptr, dwT, nullptr, out, out, nullptr, rows, DD, DFFF);
}